// Round 1
// baseline (1861.840 us; speedup 1.0000x reference)
//
#include <hip/hip_runtime.h>
#include <math.h>

// Problem constants
constexpr int Bc = 2;
constexpr int Sc = 2048;
constexpr int Dc = 1024;
constexpr int Hc = 16;
constexpr int HDc = 64;

// ---------------------------------------------------------------------------
// RoPE cos/sin table: [S][32] each, computed in double for exact angles.
// ---------------------------------------------------------------------------
__global__ void rope_table(float* __restrict__ ct, float* __restrict__ st_) {
    int id = blockIdx.x * 256 + threadIdx.x;   // 0 .. S*32-1
    int s = id >> 5;
    int i = id & 31;
    double invf = pow(10000.0, -(double)i / 32.0);
    double ang = (double)s * invf;
    ct[id] = (float)cos(ang);
    st_[id] = (float)sin(ang);
}

// ---------------------------------------------------------------------------
// RoPE apply in-place on Q and K stored [B,H,S,HD].
// pair (i, i+32): q'[i] = q[i]*c - q[i+32]*s ; q'[i+32] = q[i+32]*c + q[i]*s
// ---------------------------------------------------------------------------
__global__ void rope_apply(float* __restrict__ Qr, float* __restrict__ Kr,
                           const float* __restrict__ ct, const float* __restrict__ st_) {
    int id = blockIdx.x * 256 + threadIdx.x;   // 0 .. 2*B*H*S*32-1  (B*H*S*32 = 2^21)
    int tensor = id >> 21;
    int rem = id & ((1 << 21) - 1);
    int i = rem & 31;
    int bhs = rem >> 5;                        // (b*H + h)*S + s
    int s = bhs & (Sc - 1);
    float* p = tensor ? Kr : Qr;
    size_t base = (size_t)bhs * HDc;
    float c = ct[s * 32 + i];
    float sn = st_[s * 32 + i];
    float x0 = p[base + i];
    float x1 = p[base + i + 32];
    p[base + i] = x0 * c - x1 * sn;
    p[base + i + 32] = x1 * c + x0 * sn;
}

// ---------------------------------------------------------------------------
// 64x64-tile fp32 GEMM: C[m][n] = sum_k A[m][k] * W[n][k]   (i.e. A @ W^T)
// MODE 0: plain [M][N] store (single W/C).
// MODE 1: grid.z selects (Wq,Wk,Wv); scatter store to [B,H,S,HD].
// LDS tiles stored k-major: As[kk][row], stride 68 (16B-aligned float4, <=2-way banks)
// ---------------------------------------------------------------------------
template <int MODE>
__global__ __launch_bounds__(256) void gemm64_k(
    const float* __restrict__ A,
    const float* __restrict__ Wa, const float* __restrict__ Wb, const float* __restrict__ Wc,
    float* __restrict__ Ca, float* __restrict__ Cb, float* __restrict__ Cc) {
    constexpr int K = Dc;   // 1024
    constexpr int N = Dc;   // 1024
    __shared__ float As[16][68];
    __shared__ float Ws[16][68];

    const float* W;
    float* C;
    if (MODE == 0) {
        W = Wa; C = Ca;
    } else {
        int z = blockIdx.z;
        W = (z == 0) ? Wa : (z == 1) ? Wb : Wc;
        C = (z == 0) ? Ca : (z == 1) ? Cb : Cc;
    }

    const int t = threadIdx.x;
    const int m0 = blockIdx.y * 64;
    const int n0 = blockIdx.x * 64;
    const int lr = t >> 2;          // 0..63: tile row for staging load
    const int lc = (t & 3) << 2;    // 0,4,8,12: k offset for staging load
    const int tx = t & 15;          // micro-tile col group
    const int ty = t >> 4;          // micro-tile row group

    float acc[4][4] = {};
    const float* Arow = A + (size_t)(m0 + lr) * K + lc;
    const float* Wrow = W + (size_t)(n0 + lr) * K + lc;

    for (int k0 = 0; k0 < K; k0 += 16) {
        float4 av = *(const float4*)(Arow + k0);
        float4 wv = *(const float4*)(Wrow + k0);
        __syncthreads();
        As[lc + 0][lr] = av.x; As[lc + 1][lr] = av.y; As[lc + 2][lr] = av.z; As[lc + 3][lr] = av.w;
        Ws[lc + 0][lr] = wv.x; Ws[lc + 1][lr] = wv.y; Ws[lc + 2][lr] = wv.z; Ws[lc + 3][lr] = wv.w;
        __syncthreads();
#pragma unroll
        for (int kk = 0; kk < 16; kk++) {
            float4 a4 = *(const float4*)&As[kk][ty * 4];
            float4 b4 = *(const float4*)&Ws[kk][tx * 4];
            float a[4] = {a4.x, a4.y, a4.z, a4.w};
            float b[4] = {b4.x, b4.y, b4.z, b4.w};
#pragma unroll
            for (int i = 0; i < 4; i++)
#pragma unroll
                for (int j = 0; j < 4; j++)
                    acc[i][j] = fmaf(a[i], b[j], acc[i][j]);
        }
    }

    if (MODE == 0) {
#pragma unroll
        for (int i = 0; i < 4; i++) {
            int m = m0 + ty * 4 + i;
            float4 v = {acc[i][0], acc[i][1], acc[i][2], acc[i][3]};
            *(float4*)(C + (size_t)m * N + n0 + tx * 4) = v;
        }
    } else {
#pragma unroll
        for (int i = 0; i < 4; i++) {
            int m = m0 + ty * 4 + i;
            int b = m >> 11;            // / S
            int s = m & (Sc - 1);
            int n = n0 + tx * 4;
            int h = n >> 6;             // / HD
            int d = n & (HDc - 1);      // tx*4..tx*4+3 stay within one head
            float4 v = {acc[i][0], acc[i][1], acc[i][2], acc[i][3]};
            *(float4*)(C + (((size_t)b * Hc + h) * Sc + s) * HDc + d) = v;
        }
    }
}

// ---------------------------------------------------------------------------
// Flash-style attention, fp32. One block = one (b,h) x 64-query tile.
// Q,K,V in [B,H,S,HD]; output written to [B,S,D].
// ---------------------------------------------------------------------------
__global__ __launch_bounds__(256) void attn64(
    const float* __restrict__ Q, const float* __restrict__ K,
    const float* __restrict__ V, float* __restrict__ O) {
    __shared__ float Qs[64][68];
    __shared__ float Ks[64][68];
    __shared__ float Vs[64][68];
    __shared__ float St[64][68];
    __shared__ float m_s[64], l_s[64], alpha_s[64];

    const int t = threadIdx.x;
    const int bh = blockIdx.y;           // 0..B*H-1
    const int q0 = blockIdx.x * 64;
    const int b = bh >> 4;
    const int h = bh & (Hc - 1);
    const float* Qb = Q + (size_t)bh * Sc * HDc;
    const float* Kb = K + (size_t)bh * Sc * HDc;
    const float* Vb = V + (size_t)bh * Sc * HDc;

    // load Q tile (64 x 64 floats)
#pragma unroll
    for (int p = 0; p < 4; p++) {
        int idx = t + p * 256;
        int r = idx >> 4;
        int c = (idx & 15) << 2;
        *(float4*)&Qs[r][c] = *(const float4*)&Qb[(size_t)(q0 + r) * HDc + c];
    }
    if (t < 64) {
        m_s[t] = -INFINITY;
        l_s[t] = 0.f;
    }

    // O accumulator: thread t covers dims od..od+3, rows orow + 16*rr
    const int od = (t & 15) << 2;
    const int orow = t >> 4;             // 0..15
    const int tx = t & 15;               // score cols tx*4+j
    const int ty = t >> 4;               // score rows ty*4+i
    float o[4][4] = {};

    for (int k0 = 0; k0 < Sc; k0 += 64) {
        __syncthreads();   // previous tile fully consumed
        // stage K/V tiles
#pragma unroll
        for (int p = 0; p < 4; p++) {
            int idx = t + p * 256;
            int r = idx >> 4;
            int c = (idx & 15) << 2;
            *(float4*)&Ks[r][c] = *(const float4*)&Kb[(size_t)(k0 + r) * HDc + c];
            *(float4*)&Vs[r][c] = *(const float4*)&Vb[(size_t)(k0 + r) * HDc + c];
        }
        __syncthreads();

        // scores: St[i][j] = 0.125 * q_i . k_j
        {
            float sc[4][4] = {};
#pragma unroll
            for (int d4 = 0; d4 < 64; d4 += 4) {
                float4 a[4], bb[4];
#pragma unroll
                for (int i = 0; i < 4; i++) a[i] = *(const float4*)&Qs[ty * 4 + i][d4];
#pragma unroll
                for (int j = 0; j < 4; j++) bb[j] = *(const float4*)&Ks[tx * 4 + j][d4];
#pragma unroll
                for (int i = 0; i < 4; i++)
#pragma unroll
                    for (int j = 0; j < 4; j++)
                        sc[i][j] += a[i].x * bb[j].x + a[i].y * bb[j].y +
                                    a[i].z * bb[j].z + a[i].w * bb[j].w;
            }
#pragma unroll
            for (int i = 0; i < 4; i++)
#pragma unroll
                for (int j = 0; j < 4; j++)
                    St[ty * 4 + i][tx * 4 + j] = sc[i][j] * 0.125f;
        }
        __syncthreads();

        // online softmax, one row per lane of wave 0
        if (t < 64) {
            const int r = t;
            float m_old = m_s[r];
            float mx = m_old;
            for (int j = 0; j < 64; j++) mx = fmaxf(mx, St[r][j]);
            float alpha = expf(m_old - mx);    // expf(-inf) == 0 on first tile
            float sum = 0.f;
            for (int j = 0; j < 64; j++) {
                float p = expf(St[r][j] - mx);
                St[r][j] = p;
                sum += p;
            }
            m_s[r] = mx;
            alpha_s[r] = alpha;
            l_s[r] = l_s[r] * alpha + sum;
        }
        __syncthreads();

        // O update: o = o*alpha + P @ V_tile
#pragma unroll
        for (int rr = 0; rr < 4; rr++) {
            float a = alpha_s[orow + 16 * rr];
            o[rr][0] *= a; o[rr][1] *= a; o[rr][2] *= a; o[rr][3] *= a;
        }
        for (int j = 0; j < 64; j++) {
            float4 vv = *(const float4*)&Vs[j][od];
#pragma unroll
            for (int rr = 0; rr < 4; rr++) {
                float p = St[orow + 16 * rr][j];
                o[rr][0] = fmaf(p, vv.x, o[rr][0]);
                o[rr][1] = fmaf(p, vv.y, o[rr][1]);
                o[rr][2] = fmaf(p, vv.z, o[rr][2]);
                o[rr][3] = fmaf(p, vv.w, o[rr][3]);
            }
        }
    }

    // epilogue: normalize and write [B,S,D]
#pragma unroll
    for (int rr = 0; rr < 4; rr++) {
        int r = orow + 16 * rr;
        float inv = 1.f / l_s[r];
        int s = q0 + r;
        float4 res = {o[rr][0] * inv, o[rr][1] * inv, o[rr][2] * inv, o[rr][3] * inv};
        *(float4*)&O[((size_t)b * Sc + s) * Dc + h * HDc + od] = res;
    }
}

// ---------------------------------------------------------------------------
extern "C" void kernel_launch(void* const* d_in, const int* in_sizes, int n_in,
                              void* d_out, int out_size, void* d_ws, size_t ws_size,
                              hipStream_t stream) {
    const float* x  = (const float*)d_in[0];
    const float* Wq = (const float*)d_in[1];
    const float* Wk = (const float*)d_in[2];
    const float* Wv = (const float*)d_in[3];
    const float* Wo = (const float*)d_in[4];
    float* out = (float*)d_out;
    float* ws = (float*)d_ws;

    const size_t tsz = (size_t)Bc * Hc * Sc * HDc;   // 4194304 floats
    float* Qr = ws;              // [B,H,S,HD]
    float* Kr = Qr + tsz;
    float* Vr = Kr + tsz;
    float* AO = Vr + tsz;        // [B,S,D]
    float* ct = AO + tsz;        // [S,32]
    float* st_ = ct + (size_t)Sc * 32;

    // 1. RoPE table
    rope_table<<<dim3((Sc * 32) / 256), dim3(256), 0, stream>>>(ct, st_);
    // 2. QKV projections (fused 3-way), scatter to [B,H,S,HD]
    gemm64_k<1><<<dim3(16, 64, 3), dim3(256), 0, stream>>>(x, Wq, Wk, Wv, Qr, Kr, Vr);
    // 3. RoPE on Q and K
    rope_apply<<<dim3((2 * Bc * Hc * Sc * 32) / 256), dim3(256), 0, stream>>>(Qr, Kr, ct, st_);
    // 4. attention
    attn64<<<dim3(Sc / 64, Bc * Hc), dim3(256), 0, stream>>>(Qr, Kr, Vr, AO);
    // 5. output projection
    gemm64_k<0><<<dim3(16, 64, 1), dim3(256), 0, stream>>>(AO, Wo, Wo, Wo, out, out, out);
}

// Round 2
// 783.386 us; speedup vs baseline: 2.3767x; 2.3767x over previous
//
#include <hip/hip_runtime.h>
#include <math.h>

// Problem constants
constexpr int Bc = 2;
constexpr int Sc = 2048;
constexpr int Dc = 1024;
constexpr int Hc = 16;
constexpr int HDc = 64;

typedef __attribute__((ext_vector_type(8))) short bf16x8;
typedef __attribute__((ext_vector_type(4))) float f32x4;

// fp32 -> bf16 round-to-nearest-even (returns low 16 bits)
__device__ __forceinline__ unsigned f2bf(float x) {
    unsigned u = __float_as_uint(x);
    return (u + 0x7FFFu + ((u >> 16) & 1u)) >> 16;
}

// ---------------------------------------------------------------------------
// RoPE cos/sin table: [S][32] each, computed in double for exact angles.
// ---------------------------------------------------------------------------
__global__ void rope_table(float* __restrict__ ct, float* __restrict__ st_) {
    int id = blockIdx.x * 256 + threadIdx.x;   // 0 .. S*32-1
    int s = id >> 5;
    int i = id & 31;
    double invf = pow(10000.0, -(double)i / 32.0);
    double ang = (double)s * invf;
    ct[id] = (float)cos(ang);
    st_[id] = (float)sin(ang);
}

// ---------------------------------------------------------------------------
// RoPE apply in-place on Q and K stored [B,H,S,HD].
// ---------------------------------------------------------------------------
__global__ void rope_apply(float* __restrict__ Qr, float* __restrict__ Kr,
                           const float* __restrict__ ct, const float* __restrict__ st_) {
    int id = blockIdx.x * 256 + threadIdx.x;
    int tensor = id >> 21;
    int rem = id & ((1 << 21) - 1);
    int i = rem & 31;
    int bhs = rem >> 5;
    int s = bhs & (Sc - 1);
    float* p = tensor ? Kr : Qr;
    size_t base = (size_t)bhs * HDc;
    float c = ct[s * 32 + i];
    float sn = st_[s * 32 + i];
    float x0 = p[base + i];
    float x1 = p[base + i + 32];
    p[base + i] = x0 * c - x1 * sn;
    p[base + i + 32] = x1 * c + x0 * sn;
}

// ---------------------------------------------------------------------------
// 64x64-tile fp32 GEMM: C = A @ W^T  (unchanged from round 1)
// ---------------------------------------------------------------------------
template <int MODE>
__global__ __launch_bounds__(256) void gemm64_k(
    const float* __restrict__ A,
    const float* __restrict__ Wa, const float* __restrict__ Wb, const float* __restrict__ Wc,
    float* __restrict__ Ca, float* __restrict__ Cb, float* __restrict__ Cc) {
    constexpr int K = Dc;
    constexpr int N = Dc;
    __shared__ float As[16][68];
    __shared__ float Ws[16][68];

    const float* W;
    float* C;
    if (MODE == 0) {
        W = Wa; C = Ca;
    } else {
        int z = blockIdx.z;
        W = (z == 0) ? Wa : (z == 1) ? Wb : Wc;
        C = (z == 0) ? Ca : (z == 1) ? Cb : Cc;
    }

    const int t = threadIdx.x;
    const int m0 = blockIdx.y * 64;
    const int n0 = blockIdx.x * 64;
    const int lr = t >> 2;
    const int lc = (t & 3) << 2;
    const int tx = t & 15;
    const int ty = t >> 4;

    float acc[4][4] = {};
    const float* Arow = A + (size_t)(m0 + lr) * K + lc;
    const float* Wrow = W + (size_t)(n0 + lr) * K + lc;

    for (int k0 = 0; k0 < K; k0 += 16) {
        float4 av = *(const float4*)(Arow + k0);
        float4 wv = *(const float4*)(Wrow + k0);
        __syncthreads();
        As[lc + 0][lr] = av.x; As[lc + 1][lr] = av.y; As[lc + 2][lr] = av.z; As[lc + 3][lr] = av.w;
        Ws[lc + 0][lr] = wv.x; Ws[lc + 1][lr] = wv.y; Ws[lc + 2][lr] = wv.z; Ws[lc + 3][lr] = wv.w;
        __syncthreads();
#pragma unroll
        for (int kk = 0; kk < 16; kk++) {
            float4 a4 = *(const float4*)&As[kk][ty * 4];
            float4 b4 = *(const float4*)&Ws[kk][tx * 4];
            float a[4] = {a4.x, a4.y, a4.z, a4.w};
            float b[4] = {b4.x, b4.y, b4.z, b4.w};
#pragma unroll
            for (int i = 0; i < 4; i++)
#pragma unroll
                for (int j = 0; j < 4; j++)
                    acc[i][j] = fmaf(a[i], b[j], acc[i][j]);
        }
    }

    if (MODE == 0) {
#pragma unroll
        for (int i = 0; i < 4; i++) {
            int m = m0 + ty * 4 + i;
            float4 v = {acc[i][0], acc[i][1], acc[i][2], acc[i][3]};
            *(float4*)(C + (size_t)m * N + n0 + tx * 4) = v;
        }
    } else {
#pragma unroll
        for (int i = 0; i < 4; i++) {
            int m = m0 + ty * 4 + i;
            int b = m >> 11;
            int s = m & (Sc - 1);
            int n = n0 + tx * 4;
            int h = n >> 6;
            int d = n & (HDc - 1);
            float4 v = {acc[i][0], acc[i][1], acc[i][2], acc[i][3]};
            *(float4*)(C + (((size_t)b * Hc + h) * Sc + s) * HDc + d) = v;
        }
    }
}

// ---------------------------------------------------------------------------
// MFMA flash attention, bf16 hi/lo split (3-product ~ fp32 accuracy).
// Block = 256 threads (4 waves). Wave w owns query rows [w*16, w*16+16).
// Online softmax entirely in registers (quad shuffles). P round-trips LDS.
// ---------------------------------------------------------------------------
__global__ __launch_bounds__(256) void attn_mfma(
    const float* __restrict__ Q, const float* __restrict__ K,
    const float* __restrict__ V, float* __restrict__ O) {
    // K tiles: [kk][d], rows of 72 bf16 (144 B, 16B-aligned)
    __shared__ __align__(16) unsigned short Ks_h[64 * 72], Ks_l[64 * 72];
    // V transposed: [d][kk'], kk 8-blocks XOR-swizzled by (d>>4)
    __shared__ __align__(16) unsigned short Vt_h[64 * 72], Vt_l[64 * 72];
    // P: [q][kk], written C-layout, read A-layout (per-wave private rows)
    __shared__ __align__(16) unsigned short Ph[64 * 72], Pl[64 * 72];

    const int t = threadIdx.x;
    const int lane = t & 63;
    const int wave = t >> 6;
    const int band = wave * 16;
    const int l = lane & 15;
    const int quad = lane >> 4;
    const int bh = blockIdx.y;
    const int q0 = blockIdx.x * 64;
    const int b = bh >> 4;
    const int h = bh & (Hc - 1);
    const float* Qb = Q + (size_t)bh * Sc * HDc;
    const float* Kb = K + (size_t)bh * Sc * HDc;
    const float* Vb = V + (size_t)bh * Sc * HDc;

    // --- Q fragments: loaded once from global, pre-scaled by 0.125 (exact) ---
    bf16x8 qh[2], ql[2];
    {
        const float* qrow = Qb + (size_t)(q0 + band + l) * HDc + quad * 8;
#pragma unroll
        for (int ks = 0; ks < 2; ks++) {
#pragma unroll
            for (int j = 0; j < 8; j++) {
                float x = qrow[ks * 32 + j] * 0.125f;
                unsigned hh = f2bf(x);
                float xh = __uint_as_float(hh << 16);
                unsigned lo = f2bf(x - xh);
                qh[ks][j] = (short)hh;
                ql[ks][j] = (short)lo;
            }
        }
    }

    f32x4 o[4];
#pragma unroll
    for (int i = 0; i < 4; i++) o[i] = (f32x4){0.f, 0.f, 0.f, 0.f};
    float mrow[4] = {-INFINITY, -INFINITY, -INFINITY, -INFINITY};
    float lrow[4] = {0.f, 0.f, 0.f, 0.f};

    const int skk = t >> 2;           // staging row 0..63
    const int sdg = (t & 3) * 16;     // staging col group

    for (int k0 = 0; k0 < Sc; k0 += 64) {
        // ---- stage K (hi/lo) and V (transposed + swizzled, hi/lo) ----
#pragma unroll
        for (int i = 0; i < 4; i++) {
            float4 kv = *(const float4*)(Kb + (size_t)(k0 + skk) * HDc + sdg + i * 4);
            float4 vv = *(const float4*)(Vb + (size_t)(k0 + skk) * HDc + sdg + i * 4);
            const float* kp = (const float*)&kv;
            const float* vp = (const float*)&vv;
#pragma unroll
            for (int e = 0; e < 4; e++) {
                int d = sdg + i * 4 + e;
                float kx = kp[e];
                unsigned kh = f2bf(kx);
                unsigned klo = f2bf(kx - __uint_as_float(kh << 16));
                Ks_h[skk * 72 + d] = (unsigned short)kh;
                Ks_l[skk * 72 + d] = (unsigned short)klo;
                float vx = vp[e];
                unsigned vh = f2bf(vx);
                unsigned vlo = f2bf(vx - __uint_as_float(vh << 16));
                int cb = (skk >> 3) ^ (((d >> 4) & 3) << 1);
                int colp = (skk & 7) | (cb << 3);
                Vt_h[d * 72 + colp] = (unsigned short)vh;
                Vt_l[d * 72 + colp] = (unsigned short)vlo;
            }
        }
        __syncthreads();

        // ---- S = (Q*0.125) @ K^T  via 3-product bf16 split ----
        f32x4 s[4];
#pragma unroll
        for (int tt = 0; tt < 4; tt++) {
            f32x4 c = (f32x4){0.f, 0.f, 0.f, 0.f};
#pragma unroll
            for (int ks = 0; ks < 2; ks++) {
                const int off = (tt * 16 + l) * 72 + ks * 32 + quad * 8;
                bf16x8 kfh = *(const bf16x8*)&Ks_h[off];
                bf16x8 kfl = *(const bf16x8*)&Ks_l[off];
                c = __builtin_amdgcn_mfma_f32_16x16x32_bf16(qh[ks], kfh, c, 0, 0, 0);
                c = __builtin_amdgcn_mfma_f32_16x16x32_bf16(ql[ks], kfh, c, 0, 0, 0);
                c = __builtin_amdgcn_mfma_f32_16x16x32_bf16(qh[ks], kfl, c, 0, 0, 0);
            }
            s[tt] = c;
        }

        // ---- online softmax, in registers (rows quad*4+r, cols across quad) ----
#pragma unroll
        for (int r = 0; r < 4; r++) {
            float mx = fmaxf(fmaxf(s[0][r], s[1][r]), fmaxf(s[2][r], s[3][r]));
            mx = fmaxf(mx, __shfl_xor(mx, 1));
            mx = fmaxf(mx, __shfl_xor(mx, 2));
            mx = fmaxf(mx, __shfl_xor(mx, 4));
            mx = fmaxf(mx, __shfl_xor(mx, 8));
            mx = fmaxf(mx, mrow[r]);
            float alpha = __expf(mrow[r] - mx);   // first tile: exp(-inf)=0
            mrow[r] = mx;
            float sum = 0.f;
            int prow = (band + quad * 4 + r) * 72;
#pragma unroll
            for (int tt = 0; tt < 4; tt++) {
                float p = __expf(s[tt][r] - mx);
                sum += p;
                unsigned phh = f2bf(p);
                unsigned pll = f2bf(p - __uint_as_float(phh << 16));
                Ph[prow + tt * 16 + l] = (unsigned short)phh;
                Pl[prow + tt * 16 + l] = (unsigned short)pll;
            }
            sum += __shfl_xor(sum, 1);
            sum += __shfl_xor(sum, 2);
            sum += __shfl_xor(sum, 4);
            sum += __shfl_xor(sum, 8);
            lrow[r] = lrow[r] * alpha + sum;
            o[0][r] *= alpha;
            o[1][r] *= alpha;
            o[2][r] *= alpha;
            o[3][r] *= alpha;
        }

        // ---- O += P @ V  (3-product split; P rows are wave-private in LDS) ----
#pragma unroll
        for (int ks = 0; ks < 2; ks++) {
            const int poff = (band + l) * 72 + ks * 32 + quad * 8;
            bf16x8 aph = *(const bf16x8*)&Ph[poff];
            bf16x8 apl = *(const bf16x8*)&Pl[poff];
#pragma unroll
            for (int tt = 0; tt < 4; tt++) {
                int cb = (ks * 4 + quad) ^ ((tt & 3) << 1);
                const int off = (tt * 16 + l) * 72 + cb * 8;
                bf16x8 bvh = *(const bf16x8*)&Vt_h[off];
                bf16x8 bvl = *(const bf16x8*)&Vt_l[off];
                o[tt] = __builtin_amdgcn_mfma_f32_16x16x32_bf16(aph, bvh, o[tt], 0, 0, 0);
                o[tt] = __builtin_amdgcn_mfma_f32_16x16x32_bf16(aph, bvl, o[tt], 0, 0, 0);
                o[tt] = __builtin_amdgcn_mfma_f32_16x16x32_bf16(apl, bvh, o[tt], 0, 0, 0);
            }
        }
        __syncthreads();
    }

    // ---- epilogue: normalize, write [B,S,D] ----
#pragma unroll
    for (int r = 0; r < 4; r++) {
        float inv = 1.f / lrow[r];
        int q = q0 + band + quad * 4 + r;
#pragma unroll
        for (int tt = 0; tt < 4; tt++) {
            O[((size_t)b * Sc + q) * Dc + h * HDc + tt * 16 + l] = o[tt][r] * inv;
        }
    }
}

// ---------------------------------------------------------------------------
extern "C" void kernel_launch(void* const* d_in, const int* in_sizes, int n_in,
                              void* d_out, int out_size, void* d_ws, size_t ws_size,
                              hipStream_t stream) {
    const float* x  = (const float*)d_in[0];
    const float* Wq = (const float*)d_in[1];
    const float* Wk = (const float*)d_in[2];
    const float* Wv = (const float*)d_in[3];
    const float* Wo = (const float*)d_in[4];
    float* out = (float*)d_out;
    float* ws = (float*)d_ws;

    const size_t tsz = (size_t)Bc * Hc * Sc * HDc;   // 4194304 floats
    float* Qr = ws;              // [B,H,S,HD]
    float* Kr = Qr + tsz;
    float* Vr = Kr + tsz;
    float* AO = Vr + tsz;        // [B,S,D]
    float* ct = AO + tsz;        // [S,32]
    float* st_ = ct + (size_t)Sc * 32;

    rope_table<<<dim3((Sc * 32) / 256), dim3(256), 0, stream>>>(ct, st_);
    gemm64_k<1><<<dim3(16, 64, 3), dim3(256), 0, stream>>>(x, Wq, Wk, Wv, Qr, Kr, Vr);
    rope_apply<<<dim3((2 * Bc * Hc * Sc * 32) / 256), dim3(256), 0, stream>>>(Qr, Kr, ct, st_);
    attn_mfma<<<dim3(Sc / 64, Bc * Hc), dim3(256), 0, stream>>>(Qr, Kr, Vr, AO);
    gemm64_k<0><<<dim3(16, 64, 1), dim3(256), 0, stream>>>(AO, Wo, Wo, Wo, out, out, out);
}

// Round 3
// 556.673 us; speedup vs baseline: 3.3446x; 1.4073x over previous
//
#include <hip/hip_runtime.h>
#include <math.h>

// Problem constants
constexpr int Bc = 2;
constexpr int Sc = 2048;
constexpr int Dc = 1024;
constexpr int Hc = 16;
constexpr int HDc = 64;

typedef __attribute__((ext_vector_type(8))) short bf16x8;
typedef __attribute__((ext_vector_type(4))) float f32x4;
typedef __attribute__((ext_vector_type(4))) unsigned short us4;

// fp32 -> bf16 round-to-nearest-even (returns low 16 bits)
__device__ __forceinline__ unsigned f2bf(float x) {
    unsigned u = __float_as_uint(x);
    return (u + 0x7FFFu + ((u >> 16) & 1u)) >> 16;
}

__device__ __forceinline__ void split2(float x, unsigned short& h, unsigned short& l) {
    unsigned hh = f2bf(x);
    h = (unsigned short)hh;
    l = (unsigned short)f2bf(x - __uint_as_float(hh << 16));
}

// ---------------------------------------------------------------------------
// RoPE cos/sin table: [S][32] each, computed in double for exact angles.
// ---------------------------------------------------------------------------
__global__ void rope_table(float* __restrict__ ct, float* __restrict__ st_) {
    int id = blockIdx.x * 256 + threadIdx.x;
    int s = id >> 5;
    int i = id & 31;
    double invf = pow(10000.0, -(double)i / 32.0);
    double ang = (double)s * invf;
    ct[id] = (float)cos(ang);
    st_[id] = (float)sin(ang);
}

// ---------------------------------------------------------------------------
// RoPE apply in-place on Q and K stored [B,H,S,HD].
// ---------------------------------------------------------------------------
__global__ void rope_apply(float* __restrict__ Qr, float* __restrict__ Kr,
                           const float* __restrict__ ct, const float* __restrict__ st_) {
    int id = blockIdx.x * 256 + threadIdx.x;
    int tensor = id >> 21;
    int rem = id & ((1 << 21) - 1);
    int i = rem & 31;
    int bhs = rem >> 5;
    int s = bhs & (Sc - 1);
    float* p = tensor ? Kr : Qr;
    size_t base = (size_t)bhs * HDc;
    float c = ct[s * 32 + i];
    float sn = st_[s * 32 + i];
    float x0 = p[base + i];
    float x1 = p[base + i + 32];
    p[base + i] = x0 * c - x1 * sn;
    p[base + i + 32] = x1 * c + x0 * sn;
}

// ---------------------------------------------------------------------------
// Split fp32 -> bf16 hi/lo.  y=0: x (4M elems); y=1..4: W_{q,k,v,o} (1M each).
// ---------------------------------------------------------------------------
__global__ void split_xw(const float* __restrict__ x,
                         const float* __restrict__ Wq, const float* __restrict__ Wk,
                         const float* __restrict__ Wv, const float* __restrict__ Wo,
                         unsigned short* __restrict__ xh, unsigned short* __restrict__ xl,
                         unsigned short* __restrict__ whAll, unsigned short* __restrict__ wlAll) {
    int y = blockIdx.y;
    const float* src;
    unsigned short *h, *l;
    int n;
    if (y == 0) { src = x; h = xh; l = xl; n = 1 << 22; }
    else {
        src = (y == 1) ? Wq : (y == 2) ? Wk : (y == 3) ? Wv : Wo;
        h = whAll + (size_t)(y - 1) * (1 << 20);
        l = wlAll + (size_t)(y - 1) * (1 << 20);
        n = 1 << 20;
    }
    int i = (blockIdx.x * 256 + threadIdx.x) * 4;
    if (i >= n) return;
    float4 v = *(const float4*)(src + i);
    us4 hh, ll;
    split2(v.x, ((unsigned short*)&hh)[0], ((unsigned short*)&ll)[0]);
    split2(v.y, ((unsigned short*)&hh)[1], ((unsigned short*)&ll)[1]);
    split2(v.z, ((unsigned short*)&hh)[2], ((unsigned short*)&ll)[2]);
    split2(v.w, ((unsigned short*)&hh)[3], ((unsigned short*)&ll)[3]);
    *(us4*)(h + i) = hh;
    *(us4*)(l + i) = ll;
}

__global__ void split_ao(const float* __restrict__ src,
                         unsigned short* __restrict__ h, unsigned short* __restrict__ l) {
    int i = (blockIdx.x * 256 + threadIdx.x) * 4;
    float4 v = *(const float4*)(src + i);
    us4 hh, ll;
    split2(v.x, ((unsigned short*)&hh)[0], ((unsigned short*)&ll)[0]);
    split2(v.y, ((unsigned short*)&hh)[1], ((unsigned short*)&ll)[1]);
    split2(v.z, ((unsigned short*)&hh)[2], ((unsigned short*)&ll)[2]);
    split2(v.w, ((unsigned short*)&hh)[3], ((unsigned short*)&ll)[3]);
    *(us4*)(h + i) = hh;
    *(us4*)(l + i) = ll;
}

// ---------------------------------------------------------------------------
// MFMA split-bf16 GEMM: C[m][n] = sum_k (Ah+Al)[m][k]*(Wh+Wl)[n][k] (3-product)
// 128x128 tile, BK=32, 4 waves (2x2). global_load_lds staging, LDS [kb][row].
// MODE 0: C = [M][N] fp32.  MODE 1: z in {0,1,2} selects W/C; scatter [B,H,S,HD].
// ---------------------------------------------------------------------------
template <int MODE>
__global__ __launch_bounds__(256) void gemm_mfma(
    const unsigned short* __restrict__ Ah, const unsigned short* __restrict__ Al,
    const unsigned short* __restrict__ Wh0, const unsigned short* __restrict__ Wh1,
    const unsigned short* __restrict__ Wh2,
    const unsigned short* __restrict__ Wl0, const unsigned short* __restrict__ Wl1,
    const unsigned short* __restrict__ Wl2,
    float* __restrict__ C0, float* __restrict__ C1, float* __restrict__ C2) {
    constexpr int K = 1024;
    __shared__ __align__(16) unsigned short AsH[4096], AsL[4096], BsH[4096], BsL[4096];

    const unsigned short* Wh;
    const unsigned short* Wl;
    float* C;
    if (MODE == 0) {
        Wh = Wh0; Wl = Wl0; C = C0;
    } else {
        int z = blockIdx.z;
        Wh = (z == 0) ? Wh0 : (z == 1) ? Wh1 : Wh2;
        Wl = (z == 0) ? Wl0 : (z == 1) ? Wl1 : Wl2;
        C  = (z == 0) ? C0  : (z == 1) ? C1  : C2;
    }

    const int t = threadIdx.x;
    const int lane = t & 63;
    const int wave = t >> 6;
    const int l = lane & 15;
    const int quad = lane >> 4;
    const int wr = wave >> 1, wc = wave & 1;
    const int m0 = blockIdx.y * 128;
    const int n0 = blockIdx.x * 128;

    // 32 staging jobs (tensor x half x rowblock x kb), 8 per wave.
    const unsigned short* gsrc[8];
    const unsigned short* lds_dst[8];
#pragma unroll
    for (int q = 0; q < 8; q++) {
        int job = wave * 8 + q;
        int tensor = job >> 4;
        int half = (job >> 3) & 1;
        int rb = (job >> 2) & 1;
        int kb = job & 3;
        const unsigned short* g;
        const unsigned short* larr;
        int t0;
        if (tensor == 0) { g = half ? Al : Ah; larr = half ? AsL : AsH; t0 = m0; }
        else             { g = half ? Wl : Wh; larr = half ? BsL : BsH; t0 = n0; }
        gsrc[q] = g + (size_t)(t0 + rb * 64 + lane) * K + kb * 8;
        lds_dst[q] = larr + (kb * 128 + rb * 64) * 8;
    }

    f32x4 acc[4][4];
#pragma unroll
    for (int i = 0; i < 4; i++)
#pragma unroll
        for (int j = 0; j < 4; j++) acc[i][j] = (f32x4){0.f, 0.f, 0.f, 0.f};

    for (int k0 = 0; k0 < K; k0 += 32) {
        __syncthreads();
#pragma unroll
        for (int q = 0; q < 8; q++)
            __builtin_amdgcn_global_load_lds(
                (const __attribute__((address_space(1))) unsigned int*)(gsrc[q] + k0),
                (__attribute__((address_space(3))) unsigned int*)lds_dst[q], 16, 0, 0);
        __syncthreads();

        bf16x8 ah[4], al[4], bh[4], bl[4];
#pragma unroll
        for (int i = 0; i < 4; i++) {
            int ra = (quad * 128 + wr * 64 + i * 16 + l) * 8;
            ah[i] = *(const bf16x8*)&AsH[ra];
            al[i] = *(const bf16x8*)&AsL[ra];
            int rb2 = (quad * 128 + wc * 64 + i * 16 + l) * 8;
            bh[i] = *(const bf16x8*)&BsH[rb2];
            bl[i] = *(const bf16x8*)&BsL[rb2];
        }
#pragma unroll
        for (int i = 0; i < 4; i++)
#pragma unroll
            for (int j = 0; j < 4; j++) {
                acc[i][j] = __builtin_amdgcn_mfma_f32_16x16x32_bf16(ah[i], bh[j], acc[i][j], 0, 0, 0);
                acc[i][j] = __builtin_amdgcn_mfma_f32_16x16x32_bf16(al[i], bh[j], acc[i][j], 0, 0, 0);
                acc[i][j] = __builtin_amdgcn_mfma_f32_16x16x32_bf16(ah[i], bl[j], acc[i][j], 0, 0, 0);
            }
    }

    // epilogue: C/D layout col=lane&15, row=quad*4+reg
#pragma unroll
    for (int i = 0; i < 4; i++)
#pragma unroll
        for (int j = 0; j < 4; j++)
#pragma unroll
            for (int r = 0; r < 4; r++) {
                int m = m0 + wr * 64 + i * 16 + quad * 4 + r;
                int n = n0 + wc * 64 + j * 16 + l;
                if (MODE == 0) {
                    C[(size_t)m * Dc + n] = acc[i][j][r];
                } else {
                    int b = m >> 11;
                    int s = m & (Sc - 1);
                    int h = n >> 6;
                    int d = n & (HDc - 1);
                    C[(((size_t)b * Hc + h) * Sc + s) * HDc + d] = acc[i][j][r];
                }
            }
}

// ---------------------------------------------------------------------------
// MFMA flash attention, bf16 hi/lo split (unchanged from round 2).
// ---------------------------------------------------------------------------
__global__ __launch_bounds__(256) void attn_mfma(
    const float* __restrict__ Q, const float* __restrict__ K,
    const float* __restrict__ V, float* __restrict__ O) {
    __shared__ __align__(16) unsigned short Ks_h[64 * 72], Ks_l[64 * 72];
    __shared__ __align__(16) unsigned short Vt_h[64 * 72], Vt_l[64 * 72];
    __shared__ __align__(16) unsigned short Ph[64 * 72], Pl[64 * 72];

    const int t = threadIdx.x;
    const int lane = t & 63;
    const int wave = t >> 6;
    const int band = wave * 16;
    const int l = lane & 15;
    const int quad = lane >> 4;
    const int bh = blockIdx.y;
    const int q0 = blockIdx.x * 64;
    const int b = bh >> 4;
    const int h = bh & (Hc - 1);
    const float* Qb = Q + (size_t)bh * Sc * HDc;
    const float* Kb = K + (size_t)bh * Sc * HDc;
    const float* Vb = V + (size_t)bh * Sc * HDc;

    bf16x8 qh[2], ql[2];
    {
        const float* qrow = Qb + (size_t)(q0 + band + l) * HDc + quad * 8;
#pragma unroll
        for (int ks = 0; ks < 2; ks++) {
#pragma unroll
            for (int j = 0; j < 8; j++) {
                float x = qrow[ks * 32 + j] * 0.125f;
                unsigned hh = f2bf(x);
                float xh = __uint_as_float(hh << 16);
                unsigned lo = f2bf(x - xh);
                qh[ks][j] = (short)hh;
                ql[ks][j] = (short)lo;
            }
        }
    }

    f32x4 o[4];
#pragma unroll
    for (int i = 0; i < 4; i++) o[i] = (f32x4){0.f, 0.f, 0.f, 0.f};
    float mrow[4] = {-INFINITY, -INFINITY, -INFINITY, -INFINITY};
    float lrow[4] = {0.f, 0.f, 0.f, 0.f};

    const int skk = t >> 2;
    const int sdg = (t & 3) * 16;

    for (int k0 = 0; k0 < Sc; k0 += 64) {
#pragma unroll
        for (int i = 0; i < 4; i++) {
            float4 kv = *(const float4*)(Kb + (size_t)(k0 + skk) * HDc + sdg + i * 4);
            float4 vv = *(const float4*)(Vb + (size_t)(k0 + skk) * HDc + sdg + i * 4);
            const float* kp = (const float*)&kv;
            const float* vp = (const float*)&vv;
#pragma unroll
            for (int e = 0; e < 4; e++) {
                int d = sdg + i * 4 + e;
                float kx = kp[e];
                unsigned kh = f2bf(kx);
                unsigned klo = f2bf(kx - __uint_as_float(kh << 16));
                Ks_h[skk * 72 + d] = (unsigned short)kh;
                Ks_l[skk * 72 + d] = (unsigned short)klo;
                float vx = vp[e];
                unsigned vh = f2bf(vx);
                unsigned vlo = f2bf(vx - __uint_as_float(vh << 16));
                int cb = (skk >> 3) ^ (((d >> 4) & 3) << 1);
                int colp = (skk & 7) | (cb << 3);
                Vt_h[d * 72 + colp] = (unsigned short)vh;
                Vt_l[d * 72 + colp] = (unsigned short)vlo;
            }
        }
        __syncthreads();

        f32x4 s[4];
#pragma unroll
        for (int tt = 0; tt < 4; tt++) {
            f32x4 c = (f32x4){0.f, 0.f, 0.f, 0.f};
#pragma unroll
            for (int ks = 0; ks < 2; ks++) {
                const int off = (tt * 16 + l) * 72 + ks * 32 + quad * 8;
                bf16x8 kfh = *(const bf16x8*)&Ks_h[off];
                bf16x8 kfl = *(const bf16x8*)&Ks_l[off];
                c = __builtin_amdgcn_mfma_f32_16x16x32_bf16(qh[ks], kfh, c, 0, 0, 0);
                c = __builtin_amdgcn_mfma_f32_16x16x32_bf16(ql[ks], kfh, c, 0, 0, 0);
                c = __builtin_amdgcn_mfma_f32_16x16x32_bf16(qh[ks], kfl, c, 0, 0, 0);
            }
            s[tt] = c;
        }

#pragma unroll
        for (int r = 0; r < 4; r++) {
            float mx = fmaxf(fmaxf(s[0][r], s[1][r]), fmaxf(s[2][r], s[3][r]));
            mx = fmaxf(mx, __shfl_xor(mx, 1));
            mx = fmaxf(mx, __shfl_xor(mx, 2));
            mx = fmaxf(mx, __shfl_xor(mx, 4));
            mx = fmaxf(mx, __shfl_xor(mx, 8));
            mx = fmaxf(mx, mrow[r]);
            float alpha = __expf(mrow[r] - mx);
            mrow[r] = mx;
            float sum = 0.f;
            int prow = (band + quad * 4 + r) * 72;
#pragma unroll
            for (int tt = 0; tt < 4; tt++) {
                float p = __expf(s[tt][r] - mx);
                sum += p;
                unsigned phh = f2bf(p);
                unsigned pll = f2bf(p - __uint_as_float(phh << 16));
                Ph[prow + tt * 16 + l] = (unsigned short)phh;
                Pl[prow + tt * 16 + l] = (unsigned short)pll;
            }
            sum += __shfl_xor(sum, 1);
            sum += __shfl_xor(sum, 2);
            sum += __shfl_xor(sum, 4);
            sum += __shfl_xor(sum, 8);
            lrow[r] = lrow[r] * alpha + sum;
            o[0][r] *= alpha;
            o[1][r] *= alpha;
            o[2][r] *= alpha;
            o[3][r] *= alpha;
        }

#pragma unroll
        for (int ks = 0; ks < 2; ks++) {
            const int poff = (band + l) * 72 + ks * 32 + quad * 8;
            bf16x8 aph = *(const bf16x8*)&Ph[poff];
            bf16x8 apl = *(const bf16x8*)&Pl[poff];
#pragma unroll
            for (int tt = 0; tt < 4; tt++) {
                int cb = (ks * 4 + quad) ^ ((tt & 3) << 1);
                const int off = (tt * 16 + l) * 72 + cb * 8;
                bf16x8 bvh = *(const bf16x8*)&Vt_h[off];
                bf16x8 bvl = *(const bf16x8*)&Vt_l[off];
                o[tt] = __builtin_amdgcn_mfma_f32_16x16x32_bf16(aph, bvh, o[tt], 0, 0, 0);
                o[tt] = __builtin_amdgcn_mfma_f32_16x16x32_bf16(aph, bvl, o[tt], 0, 0, 0);
                o[tt] = __builtin_amdgcn_mfma_f32_16x16x32_bf16(apl, bvh, o[tt], 0, 0, 0);
            }
        }
        __syncthreads();
    }

#pragma unroll
    for (int r = 0; r < 4; r++) {
        float inv = 1.f / lrow[r];
        int q = q0 + band + quad * 4 + r;
#pragma unroll
        for (int tt = 0; tt < 4; tt++) {
            O[((size_t)b * Sc + q) * Dc + h * HDc + tt * 16 + l] = o[tt][r] * inv;
        }
    }
}

// ---------------------------------------------------------------------------
extern "C" void kernel_launch(void* const* d_in, const int* in_sizes, int n_in,
                              void* d_out, int out_size, void* d_ws, size_t ws_size,
                              hipStream_t stream) {
    const float* x  = (const float*)d_in[0];
    const float* Wq = (const float*)d_in[1];
    const float* Wk = (const float*)d_in[2];
    const float* Wv = (const float*)d_in[3];
    const float* Wo = (const float*)d_in[4];
    float* out = (float*)d_out;
    float* ws = (float*)d_ws;

    const size_t tsz = (size_t)Bc * Hc * Sc * HDc;   // 4194304 floats
    float* Qr = ws;              // [B,H,S,HD] fp32; reused as AOh/AOl after attn
    float* Kr = Qr + tsz;
    float* Vr = Kr + tsz;
    float* AO = Vr + tsz;        // first holds xh/xl; attn overwrites with fp32 AO
    float* ct = AO + tsz;
    float* st_ = ct + (size_t)Sc * 32;
    unsigned short* whAll = (unsigned short*)(st_ + (size_t)Sc * 32);  // 4M ush
    unsigned short* wlAll = whAll + (size_t)4 * (1 << 20);             // 4M ush

    unsigned short* xh = (unsigned short*)AO;        // 4M ush = 8 MB
    unsigned short* xl = xh + (size_t)(1 << 22);
    unsigned short* AOh = (unsigned short*)Qr;       // after attn, Qr is dead
    unsigned short* AOl = AOh + (size_t)(1 << 22);

    // 1. RoPE table
    rope_table<<<dim3((Sc * 32) / 256), dim3(256), 0, stream>>>(ct, st_);
    // 2. split x and weights to bf16 hi/lo
    split_xw<<<dim3(4096, 5), dim3(256), 0, stream>>>(x, Wq, Wk, Wv, Wo, xh, xl, whAll, wlAll);
    // 3. QKV projections (MFMA), scatter to [B,H,S,HD] fp32
    gemm_mfma<1><<<dim3(8, 32, 3), dim3(256), 0, stream>>>(
        xh, xl,
        whAll, whAll + (1 << 20), whAll + 2 * (1 << 20),
        wlAll, wlAll + (1 << 20), wlAll + 2 * (1 << 20),
        Qr, Kr, Vr);
    // 4. RoPE on Q and K
    rope_apply<<<dim3((2 * Bc * Hc * Sc * 32) / 256), dim3(256), 0, stream>>>(Qr, Kr, ct, st_);
    // 5. attention -> AO fp32 [B,S,D]
    attn_mfma<<<dim3(Sc / 64, Bc * Hc), dim3(256), 0, stream>>>(Qr, Kr, Vr, AO);
    // 6. split AO
    split_ao<<<dim3(4096), dim3(256), 0, stream>>>(AO, AOh, AOl);
    // 7. output projection (MFMA)
    gemm_mfma<0><<<dim3(8, 32, 1), dim3(256), 0, stream>>>(
        AOh, AOl,
        whAll + 3 * (1 << 20), nullptr, nullptr,
        wlAll + 3 * (1 << 20), nullptr, nullptr,
        out, nullptr, nullptr);
}

// Round 4
// 508.095 us; speedup vs baseline: 3.6644x; 1.0956x over previous
//
#include <hip/hip_runtime.h>
#include <math.h>

// Problem constants
constexpr int Bc = 2;
constexpr int Sc = 2048;
constexpr int Dc = 1024;
constexpr int Hc = 16;
constexpr int HDc = 64;

typedef __attribute__((ext_vector_type(8))) short bf16x8;
typedef __attribute__((ext_vector_type(4))) float f32x4;
typedef __attribute__((ext_vector_type(4))) unsigned short us4;
typedef __attribute__((ext_vector_type(8))) unsigned short us8;

// fp32 -> bf16 round-to-nearest-even (returns low 16 bits)
__device__ __forceinline__ unsigned f2bf(float x) {
    unsigned u = __float_as_uint(x);
    return (u + 0x7FFFu + ((u >> 16) & 1u)) >> 16;
}

__device__ __forceinline__ void split2(float x, unsigned short& h, unsigned short& l) {
    unsigned hh = f2bf(x);
    h = (unsigned short)hh;
    l = (unsigned short)f2bf(x - __uint_as_float(hh << 16));
}

// ---------------------------------------------------------------------------
// RoPE cos/sin table: [S][32] each, double precision angles.
// ---------------------------------------------------------------------------
__global__ void rope_table(float* __restrict__ ct, float* __restrict__ st_) {
    int id = blockIdx.x * 256 + threadIdx.x;
    int s = id >> 5;
    int i = id & 31;
    double invf = pow(10000.0, -(double)i / 32.0);
    double ang = (double)s * invf;
    ct[id] = (float)cos(ang);
    st_[id] = (float)sin(ang);
}

// ---------------------------------------------------------------------------
// Split fp32 -> bf16 hi/lo.  y=0: x (4M elems); y=1..4: W_{q,k,v,o} (1M each).
// ---------------------------------------------------------------------------
__global__ void split_xw(const float* __restrict__ x,
                         const float* __restrict__ Wq, const float* __restrict__ Wk,
                         const float* __restrict__ Wv, const float* __restrict__ Wo,
                         unsigned short* __restrict__ xh, unsigned short* __restrict__ xl,
                         unsigned short* __restrict__ whAll, unsigned short* __restrict__ wlAll) {
    int y = blockIdx.y;
    const float* src;
    unsigned short *h, *l;
    int n;
    if (y == 0) { src = x; h = xh; l = xl; n = 1 << 22; }
    else {
        src = (y == 1) ? Wq : (y == 2) ? Wk : (y == 3) ? Wv : Wo;
        h = whAll + (size_t)(y - 1) * (1 << 20);
        l = wlAll + (size_t)(y - 1) * (1 << 20);
        n = 1 << 20;
    }
    int i = (blockIdx.x * 256 + threadIdx.x) * 4;
    if (i >= n) return;
    float4 v = *(const float4*)(src + i);
    us4 hh, ll;
    split2(v.x, ((unsigned short*)&hh)[0], ((unsigned short*)&ll)[0]);
    split2(v.y, ((unsigned short*)&hh)[1], ((unsigned short*)&ll)[1]);
    split2(v.z, ((unsigned short*)&hh)[2], ((unsigned short*)&ll)[2]);
    split2(v.w, ((unsigned short*)&hh)[3], ((unsigned short*)&ll)[3]);
    *(us4*)(h + i) = hh;
    *(us4*)(l + i) = ll;
}

// ---------------------------------------------------------------------------
// QKV GEMM (MFMA split-bf16, 3-product), 128x128 tile, BK=32, 4 waves.
// Fused epilogue: z=0 -> RoPE+scale Q -> Qh/Ql row-major [bh][s][64]
//                 z=1 -> RoPE K      -> Kh/Kl tiled cells [bh][T][kb][tok][8]
//                 z=2 -> V           -> Vh/Vl row-major (transposed later)
// ---------------------------------------------------------------------------
__global__ __launch_bounds__(256) void gemm_qkv(
    const unsigned short* __restrict__ Ah, const unsigned short* __restrict__ Al,
    const unsigned short* __restrict__ whAll, const unsigned short* __restrict__ wlAll,
    unsigned short* __restrict__ Qh, unsigned short* __restrict__ Ql,
    unsigned short* __restrict__ Kh, unsigned short* __restrict__ Kl,
    unsigned short* __restrict__ Vh, unsigned short* __restrict__ Vl,
    const float* __restrict__ ct, const float* __restrict__ st_) {
    constexpr int K = 1024;
    __shared__ __align__(16) unsigned short AsH[4096], AsL[4096], BsH[4096], BsL[4096];

    const int z = blockIdx.z;
    const unsigned short* Wh = whAll + (size_t)z * (1 << 20);
    const unsigned short* Wl = wlAll + (size_t)z * (1 << 20);

    const int t = threadIdx.x;
    const int lane = t & 63;
    const int wave = t >> 6;
    const int l = lane & 15;
    const int quad = lane >> 4;
    const int wr = wave >> 1, wc = wave & 1;
    const int m0 = blockIdx.y * 128;
    const int n0 = blockIdx.x * 128;

    const unsigned short* gsrc[8];
    const unsigned short* lds_dst[8];
#pragma unroll
    for (int q = 0; q < 8; q++) {
        int job = wave * 8 + q;
        int tensor = job >> 4;
        int half = (job >> 3) & 1;
        int rb = (job >> 2) & 1;
        int kb = job & 3;
        const unsigned short* g;
        const unsigned short* larr;
        int t0;
        if (tensor == 0) { g = half ? Al : Ah; larr = half ? AsL : AsH; t0 = m0; }
        else             { g = half ? Wl : Wh; larr = half ? BsL : BsH; t0 = n0; }
        gsrc[q] = g + (size_t)(t0 + rb * 64 + lane) * K + kb * 8;
        lds_dst[q] = larr + (kb * 128 + rb * 64) * 8;
    }

    f32x4 acc[4][4];
#pragma unroll
    for (int i = 0; i < 4; i++)
#pragma unroll
        for (int j = 0; j < 4; j++) acc[i][j] = (f32x4){0.f, 0.f, 0.f, 0.f};

    for (int k0 = 0; k0 < K; k0 += 32) {
        __syncthreads();
#pragma unroll
        for (int q = 0; q < 8; q++)
            __builtin_amdgcn_global_load_lds(
                (const __attribute__((address_space(1))) unsigned int*)(gsrc[q] + k0),
                (__attribute__((address_space(3))) unsigned int*)lds_dst[q], 16, 0, 0);
        __syncthreads();

        bf16x8 ah[4], al[4], bh[4], bl[4];
#pragma unroll
        for (int i = 0; i < 4; i++) {
            int ra = (quad * 128 + wr * 64 + i * 16 + l) * 8;
            ah[i] = *(const bf16x8*)&AsH[ra];
            al[i] = *(const bf16x8*)&AsL[ra];
            int rb2 = (quad * 128 + wc * 64 + i * 16 + l) * 8;
            bh[i] = *(const bf16x8*)&BsH[rb2];
            bl[i] = *(const bf16x8*)&BsL[rb2];
        }
#pragma unroll
        for (int i = 0; i < 4; i++)
#pragma unroll
            for (int j = 0; j < 4; j++) {
                acc[i][j] = __builtin_amdgcn_mfma_f32_16x16x32_bf16(ah[i], bh[j], acc[i][j], 0, 0, 0);
                acc[i][j] = __builtin_amdgcn_mfma_f32_16x16x32_bf16(al[i], bh[j], acc[i][j], 0, 0, 0);
                acc[i][j] = __builtin_amdgcn_mfma_f32_16x16x32_bf16(ah[i], bl[j], acc[i][j], 0, 0, 0);
            }
    }

    // ---- fused epilogue ----
    const int hcol = ((n0 + wc * 64) >> 6);   // head index 0..15
    if (z == 2) {
        // V: plain split, row-major [bh][s][64]
#pragma unroll
        for (int i = 0; i < 4; i++)
#pragma unroll
            for (int r = 0; r < 4; r++) {
                int m = m0 + wr * 64 + i * 16 + quad * 4 + r;
                int b = m >> 11, s = m & (Sc - 1);
                size_t rowb = (((size_t)(b * Hc + hcol)) * Sc + s) * HDc;
#pragma unroll
                for (int j = 0; j < 4; j++) {
                    int d = j * 16 + l;
                    unsigned short vh, vl;
                    split2(acc[i][j][r], vh, vl);
                    Vh[rowb + d] = vh;
                    Vl[rowb + d] = vl;
                }
            }
    } else {
#pragma unroll
        for (int i = 0; i < 4; i++)
#pragma unroll
            for (int r = 0; r < 4; r++) {
                int m = m0 + wr * 64 + i * 16 + quad * 4 + r;
                int b = m >> 11, s = m & (Sc - 1);
#pragma unroll
                for (int jp = 0; jp < 2; jp++) {
                    int d = jp * 16 + l;                       // 0..31
                    float cs = ct[s * 32 + d];
                    float sn = st_[s * 32 + d];
                    float x0 = acc[i][jp][r];
                    float x1 = acc[i][jp + 2][r];
                    float y0 = x0 * cs - x1 * sn;
                    float y1 = x1 * cs + x0 * sn;
                    if (z == 0) {
                        y0 *= 0.125f; y1 *= 0.125f;
                        size_t rowb = (((size_t)(b * Hc + hcol)) * Sc + s) * HDc;
                        unsigned short h_, l_;
                        split2(y0, h_, l_); Qh[rowb + d] = h_; Ql[rowb + d] = l_;
                        split2(y1, h_, l_); Qh[rowb + d + 32] = h_; Ql[rowb + d + 32] = l_;
                    } else {
                        int T = s >> 6, tok = s & 63;
                        size_t tb = (((size_t)(b * Hc + hcol)) * 32 + T) * 8;
                        size_t off0 = ((tb + (d >> 3)) * 64 + tok) * 8 + (d & 7);
                        size_t off1 = ((tb + (d >> 3) + 4) * 64 + tok) * 8 + (d & 7);
                        unsigned short h_, l_;
                        split2(y0, h_, l_); Kh[off0] = h_; Kl[off0] = l_;
                        split2(y1, h_, l_); Kh[off1] = h_; Kl[off1] = l_;
                    }
                }
            }
    }
}

// ---------------------------------------------------------------------------
// In-place per-tile transpose of V: row cells [tok][d] -> V^T cells [kkb][d][kk].
// One block per (bh, tile): 8 KB h + 8 KB l.
// ---------------------------------------------------------------------------
__global__ __launch_bounds__(256) void prep_v(unsigned short* __restrict__ Vh,
                                              unsigned short* __restrict__ Vl) {
    __shared__ __align__(16) unsigned short Lh[64 * 72], Ll[64 * 72];
    const size_t base = (size_t)blockIdx.x * 4096;
    const int t = threadIdx.x;
#pragma unroll
    for (int p = 0; p < 2; p++) {
        int idx = (t + p * 256) * 8;              // element offset, multiple of 8
        int tok = idx >> 6;
        int d0 = idx & 63;
        *(us8*)&Lh[tok * 72 + d0] = *(const us8*)(Vh + base + idx);
        *(us8*)&Ll[tok * 72 + d0] = *(const us8*)(Vl + base + idx);
    }
    __syncthreads();
#pragma unroll
    for (int p = 0; p < 2; p++) {
        int c = t + p * 256;                      // cell 0..511
        int kkb = c >> 6;
        int d = c & 63;
        us8 oh, ol;
#pragma unroll
        for (int kk = 0; kk < 8; kk++) {
            oh[kk] = Lh[(kkb * 8 + kk) * 72 + d];
            ol[kk] = Ll[(kkb * 8 + kk) * 72 + d];
        }
        *(us8*)(Vh + base + c * 8) = oh;
        *(us8*)(Vl + base + c * 8) = ol;
    }
}

// ---------------------------------------------------------------------------
// MFMA flash attention v2: K/V staged by global_load_lds DMA (pre-converted
// bf16 hi/lo, LDS-image cell layout). Zero VALU staging.
// ---------------------------------------------------------------------------
__global__ __launch_bounds__(256) void attn2(
    const unsigned short* __restrict__ Qh, const unsigned short* __restrict__ Ql,
    const unsigned short* __restrict__ Kh, const unsigned short* __restrict__ Kl,
    const unsigned short* __restrict__ Vh, const unsigned short* __restrict__ Vl,
    unsigned short* __restrict__ AOh, unsigned short* __restrict__ AOl) {
    __shared__ __align__(16) unsigned short KsH[4096], KsL[4096], VtH[4096], VtL[4096];
    __shared__ __align__(16) unsigned short Ph[64 * 72], Pl[64 * 72];

    const int t = threadIdx.x;
    const int lane = t & 63;
    const int wave = t >> 6;
    const int band = wave * 16;
    const int l = lane & 15;
    const int quad = lane >> 4;
    const int bh = blockIdx.y;
    const int q0 = blockIdx.x * 64;
    const int b = bh >> 4;
    const int hh = bh & (Hc - 1);

    // Q fragments straight from global (pre-RoPE'd, pre-scaled, split)
    bf16x8 qh[2], ql[2];
    {
        size_t rowb = ((size_t)bh * Sc + q0 + band + l) * HDc;
#pragma unroll
        for (int ks = 0; ks < 2; ks++) {
            qh[ks] = *(const bf16x8*)(Qh + rowb + ks * 32 + quad * 8);
            ql[ks] = *(const bf16x8*)(Ql + rowb + ks * 32 + quad * 8);
        }
    }

    f32x4 o[4];
#pragma unroll
    for (int i = 0; i < 4; i++) o[i] = (f32x4){0.f, 0.f, 0.f, 0.f};
    float mrow[4] = {-INFINITY, -INFINITY, -INFINITY, -INFINITY};
    float lrow[4] = {0.f, 0.f, 0.f, 0.f};

    const unsigned short* KhB = Kh + (size_t)bh * Sc * HDc;
    const unsigned short* KlB = Kl + (size_t)bh * Sc * HDc;
    const unsigned short* VhB = Vh + (size_t)bh * Sc * HDc;
    const unsigned short* VlB = Vl + (size_t)bh * Sc * HDc;

    for (int kt = 0; kt < 32; kt++) {
        __syncthreads();
        const size_t tb = (size_t)kt * 4096;
#pragma unroll
        for (int p = 0; p < 2; p++) {
            int c = wave * 2 + p;                  // chunk 0..7, 512 elems each
            int go = c * 512 + lane * 8;
            __builtin_amdgcn_global_load_lds(
                (const __attribute__((address_space(1))) unsigned int*)(KhB + tb + go),
                (__attribute__((address_space(3))) unsigned int*)&KsH[c * 512], 16, 0, 0);
            __builtin_amdgcn_global_load_lds(
                (const __attribute__((address_space(1))) unsigned int*)(KlB + tb + go),
                (__attribute__((address_space(3))) unsigned int*)&KsL[c * 512], 16, 0, 0);
            __builtin_amdgcn_global_load_lds(
                (const __attribute__((address_space(1))) unsigned int*)(VhB + tb + go),
                (__attribute__((address_space(3))) unsigned int*)&VtH[c * 512], 16, 0, 0);
            __builtin_amdgcn_global_load_lds(
                (const __attribute__((address_space(1))) unsigned int*)(VlB + tb + go),
                (__attribute__((address_space(3))) unsigned int*)&VtL[c * 512], 16, 0, 0);
        }
        __syncthreads();

        // ---- S = Q @ K^T (3-product) ----
        f32x4 s[4];
#pragma unroll
        for (int tt = 0; tt < 4; tt++) {
            f32x4 c = (f32x4){0.f, 0.f, 0.f, 0.f};
#pragma unroll
            for (int ks = 0; ks < 2; ks++) {
                const int off = ((ks * 4 + quad) * 64 + tt * 16 + l) * 8;
                bf16x8 kfh = *(const bf16x8*)&KsH[off];
                bf16x8 kfl = *(const bf16x8*)&KsL[off];
                c = __builtin_amdgcn_mfma_f32_16x16x32_bf16(qh[ks], kfh, c, 0, 0, 0);
                c = __builtin_amdgcn_mfma_f32_16x16x32_bf16(ql[ks], kfh, c, 0, 0, 0);
                c = __builtin_amdgcn_mfma_f32_16x16x32_bf16(qh[ks], kfl, c, 0, 0, 0);
            }
            s[tt] = c;
        }

        // ---- online softmax in registers ----
#pragma unroll
        for (int r = 0; r < 4; r++) {
            float mx = fmaxf(fmaxf(s[0][r], s[1][r]), fmaxf(s[2][r], s[3][r]));
            mx = fmaxf(mx, __shfl_xor(mx, 1));
            mx = fmaxf(mx, __shfl_xor(mx, 2));
            mx = fmaxf(mx, __shfl_xor(mx, 4));
            mx = fmaxf(mx, __shfl_xor(mx, 8));
            mx = fmaxf(mx, mrow[r]);
            float alpha = __expf(mrow[r] - mx);
            mrow[r] = mx;
            float sum = 0.f;
            int prow = (band + quad * 4 + r) * 72;
#pragma unroll
            for (int tt = 0; tt < 4; tt++) {
                float p = __expf(s[tt][r] - mx);
                sum += p;
                unsigned phh = f2bf(p);
                unsigned pll = f2bf(p - __uint_as_float(phh << 16));
                Ph[prow + tt * 16 + l] = (unsigned short)phh;
                Pl[prow + tt * 16 + l] = (unsigned short)pll;
            }
            sum += __shfl_xor(sum, 1);
            sum += __shfl_xor(sum, 2);
            sum += __shfl_xor(sum, 4);
            sum += __shfl_xor(sum, 8);
            lrow[r] = lrow[r] * alpha + sum;
            o[0][r] *= alpha;
            o[1][r] *= alpha;
            o[2][r] *= alpha;
            o[3][r] *= alpha;
        }

        // ---- O += P @ V (3-product) ----
#pragma unroll
        for (int ks = 0; ks < 2; ks++) {
            const int poff = (band + l) * 72 + ks * 32 + quad * 8;
            bf16x8 aph = *(const bf16x8*)&Ph[poff];
            bf16x8 apl = *(const bf16x8*)&Pl[poff];
#pragma unroll
            for (int tt = 0; tt < 4; tt++) {
                const int off = ((ks * 4 + quad) * 64 + tt * 16 + l) * 8;
                bf16x8 bvh = *(const bf16x8*)&VtH[off];
                bf16x8 bvl = *(const bf16x8*)&VtL[off];
                o[tt] = __builtin_amdgcn_mfma_f32_16x16x32_bf16(aph, bvh, o[tt], 0, 0, 0);
                o[tt] = __builtin_amdgcn_mfma_f32_16x16x32_bf16(aph, bvl, o[tt], 0, 0, 0);
                o[tt] = __builtin_amdgcn_mfma_f32_16x16x32_bf16(apl, bvh, o[tt], 0, 0, 0);
            }
        }
    }

    // ---- epilogue: normalize + split to bf16 hi/lo [B,S,D] ----
#pragma unroll
    for (int r = 0; r < 4; r++) {
        float inv = 1.f / lrow[r];
        int q = q0 + band + quad * 4 + r;
        size_t rowb = ((size_t)b * Sc + q) * Dc + hh * HDc;
#pragma unroll
        for (int tt = 0; tt < 4; tt++) {
            unsigned short h_, l_;
            split2(o[tt][r] * inv, h_, l_);
            AOh[rowb + tt * 16 + l] = h_;
            AOl[rowb + tt * 16 + l] = l_;
        }
    }
}

// ---------------------------------------------------------------------------
// Output projection GEMM (MFMA split-bf16), fp32 store.
// ---------------------------------------------------------------------------
__global__ __launch_bounds__(256) void gemm_out(
    const unsigned short* __restrict__ Ah, const unsigned short* __restrict__ Al,
    const unsigned short* __restrict__ Wh, const unsigned short* __restrict__ Wl,
    float* __restrict__ C) {
    constexpr int K = 1024;
    __shared__ __align__(16) unsigned short AsH[4096], AsL[4096], BsH[4096], BsL[4096];

    const int t = threadIdx.x;
    const int lane = t & 63;
    const int wave = t >> 6;
    const int l = lane & 15;
    const int quad = lane >> 4;
    const int wr = wave >> 1, wc = wave & 1;
    const int m0 = blockIdx.y * 128;
    const int n0 = blockIdx.x * 128;

    const unsigned short* gsrc[8];
    const unsigned short* lds_dst[8];
#pragma unroll
    for (int q = 0; q < 8; q++) {
        int job = wave * 8 + q;
        int tensor = job >> 4;
        int half = (job >> 3) & 1;
        int rb = (job >> 2) & 1;
        int kb = job & 3;
        const unsigned short* g;
        const unsigned short* larr;
        int t0;
        if (tensor == 0) { g = half ? Al : Ah; larr = half ? AsL : AsH; t0 = m0; }
        else             { g = half ? Wl : Wh; larr = half ? BsL : BsH; t0 = n0; }
        gsrc[q] = g + (size_t)(t0 + rb * 64 + lane) * K + kb * 8;
        lds_dst[q] = larr + (kb * 128 + rb * 64) * 8;
    }

    f32x4 acc[4][4];
#pragma unroll
    for (int i = 0; i < 4; i++)
#pragma unroll
        for (int j = 0; j < 4; j++) acc[i][j] = (f32x4){0.f, 0.f, 0.f, 0.f};

    for (int k0 = 0; k0 < K; k0 += 32) {
        __syncthreads();
#pragma unroll
        for (int q = 0; q < 8; q++)
            __builtin_amdgcn_global_load_lds(
                (const __attribute__((address_space(1))) unsigned int*)(gsrc[q] + k0),
                (__attribute__((address_space(3))) unsigned int*)lds_dst[q], 16, 0, 0);
        __syncthreads();

        bf16x8 ah[4], al[4], bh[4], bl[4];
#pragma unroll
        for (int i = 0; i < 4; i++) {
            int ra = (quad * 128 + wr * 64 + i * 16 + l) * 8;
            ah[i] = *(const bf16x8*)&AsH[ra];
            al[i] = *(const bf16x8*)&AsL[ra];
            int rb2 = (quad * 128 + wc * 64 + i * 16 + l) * 8;
            bh[i] = *(const bf16x8*)&BsH[rb2];
            bl[i] = *(const bf16x8*)&BsL[rb2];
        }
#pragma unroll
        for (int i = 0; i < 4; i++)
#pragma unroll
            for (int j = 0; j < 4; j++) {
                acc[i][j] = __builtin_amdgcn_mfma_f32_16x16x32_bf16(ah[i], bh[j], acc[i][j], 0, 0, 0);
                acc[i][j] = __builtin_amdgcn_mfma_f32_16x16x32_bf16(al[i], bh[j], acc[i][j], 0, 0, 0);
                acc[i][j] = __builtin_amdgcn_mfma_f32_16x16x32_bf16(ah[i], bl[j], acc[i][j], 0, 0, 0);
            }
    }

#pragma unroll
    for (int i = 0; i < 4; i++)
#pragma unroll
        for (int j = 0; j < 4; j++)
#pragma unroll
            for (int r = 0; r < 4; r++) {
                int m = m0 + wr * 64 + i * 16 + quad * 4 + r;
                int n = n0 + wc * 64 + j * 16 + l;
                C[(size_t)m * Dc + n] = acc[i][j][r];
            }
}

// ---------------------------------------------------------------------------
extern "C" void kernel_launch(void* const* d_in, const int* in_sizes, int n_in,
                              void* d_out, int out_size, void* d_ws, size_t ws_size,
                              hipStream_t stream) {
    const float* x  = (const float*)d_in[0];
    const float* Wq = (const float*)d_in[1];
    const float* Wk = (const float*)d_in[2];
    const float* Wv = (const float*)d_in[3];
    const float* Wo = (const float*)d_in[4];
    float* out = (float*)d_out;

    unsigned short* usw = (unsigned short*)d_ws;
    const size_t M4 = (size_t)1 << 22;   // 4M elements
    unsigned short* whAll = usw;                 // 4 x 1M weights hi
    unsigned short* wlAll = usw + M4;            // lo
    unsigned short* xh = usw + 2 * M4;           // x hi  (later AOh)
    unsigned short* xl = usw + 3 * M4;           // x lo  (later AOl)
    unsigned short* Qh = usw + 4 * M4;
    unsigned short* Ql = usw + 5 * M4;
    unsigned short* Kh = usw + 6 * M4;
    unsigned short* Kl = usw + 7 * M4;
    unsigned short* Vh = usw + 8 * M4;
    unsigned short* Vl = usw + 9 * M4;
    float* ct = (float*)(usw + 10 * M4);
    float* st_ = ct + (size_t)Sc * 32;
    unsigned short* AOh = xh;   // x dead after QKV GEMM
    unsigned short* AOl = xl;

    // 1. RoPE table
    rope_table<<<dim3((Sc * 32) / 256), dim3(256), 0, stream>>>(ct, st_);
    // 2. split x + weights to bf16 hi/lo
    split_xw<<<dim3(4096, 5), dim3(256), 0, stream>>>(x, Wq, Wk, Wv, Wo, xh, xl, whAll, wlAll);
    // 3. QKV projections with fused RoPE/scale/split epilogues
    gemm_qkv<<<dim3(8, 32, 3), dim3(256), 0, stream>>>(
        xh, xl, whAll, wlAll, Qh, Ql, Kh, Kl, Vh, Vl, ct, st_);
    // 4. transpose V tiles in place to V^T cell layout
    prep_v<<<dim3(Bc * Hc * 32), dim3(256), 0, stream>>>(Vh, Vl);
    // 5. attention (DMA-staged) -> AOh/AOl bf16 hi/lo
    attn2<<<dim3(Sc / 64, Bc * Hc), dim3(256), 0, stream>>>(
        Qh, Ql, Kh, Kl, Vh, Vl, AOh, AOl);
    // 6. output projection
    gemm_out<<<dim3(8, 32), dim3(256), 0, stream>>>(
        AOh, AOl, whAll + 3 * (1 << 20), wlAll + 3 * (1 << 20), out);
}

// Round 5
// 457.670 us; speedup vs baseline: 4.0681x; 1.1102x over previous
//
#include <hip/hip_runtime.h>
#include <math.h>

// Problem constants
constexpr int Bc = 2;
constexpr int Sc = 2048;
constexpr int Dc = 1024;
constexpr int Hc = 16;
constexpr int HDc = 64;

// Q pre-scale: attention 1/sqrt(64) folded with log2(e) for exp2-domain softmax
constexpr float QSC = 0.125f * 1.4426950408889634f;

typedef __attribute__((ext_vector_type(8))) short bf16x8;
typedef __attribute__((ext_vector_type(4))) float f32x4;
typedef __attribute__((ext_vector_type(4))) unsigned short us4;

// fp32 -> bf16 round-to-nearest-even (returns low 16 bits)
__device__ __forceinline__ unsigned f2bf(float x) {
    unsigned u = __float_as_uint(x);
    return (u + 0x7FFFu + ((u >> 16) & 1u)) >> 16;
}

__device__ __forceinline__ void split2(float x, unsigned short& h, unsigned short& l) {
    unsigned hh = f2bf(x);
    h = (unsigned short)hh;
    l = (unsigned short)f2bf(x - __uint_as_float(hh << 16));
}

// DPP max-fold within 16-lane rows (moves reductions off the LDS pipe)
template <int CTRL>
__device__ __forceinline__ float maxdpp(float x) {
    int y = __builtin_amdgcn_update_dpp(0, __float_as_int(x), CTRL, 0xF, 0xF, false);
    return fmaxf(x, __int_as_float(y));
}

// ---------------------------------------------------------------------------
// RoPE cos/sin table: [S][32] each, double precision angles.
// ---------------------------------------------------------------------------
__global__ void rope_table(float* __restrict__ ct, float* __restrict__ st_) {
    int id = blockIdx.x * 256 + threadIdx.x;
    int s = id >> 5;
    int i = id & 31;
    double invf = pow(10000.0, -(double)i / 32.0);
    double ang = (double)s * invf;
    ct[id] = (float)cos(ang);
    st_[id] = (float)sin(ang);
}

// ---------------------------------------------------------------------------
// Split fp32 -> bf16 hi/lo.  y=0: x (4M elems); y=1..4: W_{q,k,v,o} (1M each).
// ---------------------------------------------------------------------------
__global__ void split_xw(const float* __restrict__ x,
                         const float* __restrict__ Wq, const float* __restrict__ Wk,
                         const float* __restrict__ Wv, const float* __restrict__ Wo,
                         unsigned short* __restrict__ xh, unsigned short* __restrict__ xl,
                         unsigned short* __restrict__ whAll, unsigned short* __restrict__ wlAll) {
    int y = blockIdx.y;
    const float* src;
    unsigned short *h, *l;
    int n;
    if (y == 0) { src = x; h = xh; l = xl; n = 1 << 22; }
    else {
        src = (y == 1) ? Wq : (y == 2) ? Wk : (y == 3) ? Wv : Wo;
        h = whAll + (size_t)(y - 1) * (1 << 20);
        l = wlAll + (size_t)(y - 1) * (1 << 20);
        n = 1 << 20;
    }
    int i = (blockIdx.x * 256 + threadIdx.x) * 4;
    if (i >= n) return;
    float4 v = *(const float4*)(src + i);
    us4 hh, ll;
    split2(v.x, ((unsigned short*)&hh)[0], ((unsigned short*)&ll)[0]);
    split2(v.y, ((unsigned short*)&hh)[1], ((unsigned short*)&ll)[1]);
    split2(v.z, ((unsigned short*)&hh)[2], ((unsigned short*)&ll)[2]);
    split2(v.w, ((unsigned short*)&hh)[3], ((unsigned short*)&ll)[3]);
    *(us4*)(h + i) = hh;
    *(us4*)(l + i) = ll;
}

// ---------------------------------------------------------------------------
// QKV GEMM (MFMA split-bf16, 3-product), 128x128 tile, BK=32, 4 waves.
// Fused epilogue: z=0 -> RoPE + QSC scale Q -> Qh/Ql row-major [bh][s][64]
//                 z=1 -> RoPE K  -> Kh/Kl tiled cells [bh][T][kb][tok][8]
//                 z=2 -> V       -> Vh/Vl V^T tiled cells [bh][T][kkb][d][kk]
// ---------------------------------------------------------------------------
__global__ __launch_bounds__(256) void gemm_qkv(
    const unsigned short* __restrict__ Ah, const unsigned short* __restrict__ Al,
    const unsigned short* __restrict__ whAll, const unsigned short* __restrict__ wlAll,
    unsigned short* __restrict__ Qh, unsigned short* __restrict__ Ql,
    unsigned short* __restrict__ Kh, unsigned short* __restrict__ Kl,
    unsigned short* __restrict__ Vh, unsigned short* __restrict__ Vl,
    const float* __restrict__ ct, const float* __restrict__ st_) {
    constexpr int K = 1024;
    __shared__ __align__(16) unsigned short AsH[4096], AsL[4096], BsH[4096], BsL[4096];

    const int z = blockIdx.z;
    const unsigned short* Wh = whAll + (size_t)z * (1 << 20);
    const unsigned short* Wl = wlAll + (size_t)z * (1 << 20);

    const int t = threadIdx.x;
    const int lane = t & 63;
    const int wave = t >> 6;
    const int l = lane & 15;
    const int quad = lane >> 4;
    const int wr = wave >> 1, wc = wave & 1;
    const int m0 = blockIdx.y * 128;
    const int n0 = blockIdx.x * 128;

    const unsigned short* gsrc[8];
    const unsigned short* lds_dst[8];
#pragma unroll
    for (int q = 0; q < 8; q++) {
        int job = wave * 8 + q;
        int tensor = job >> 4;
        int half = (job >> 3) & 1;
        int rb = (job >> 2) & 1;
        int kb = job & 3;
        const unsigned short* g;
        const unsigned short* larr;
        int t0;
        if (tensor == 0) { g = half ? Al : Ah; larr = half ? AsL : AsH; t0 = m0; }
        else             { g = half ? Wl : Wh; larr = half ? BsL : BsH; t0 = n0; }
        gsrc[q] = g + (size_t)(t0 + rb * 64 + lane) * K + kb * 8;
        lds_dst[q] = larr + (kb * 128 + rb * 64) * 8;
    }

    f32x4 acc[4][4];
#pragma unroll
    for (int i = 0; i < 4; i++)
#pragma unroll
        for (int j = 0; j < 4; j++) acc[i][j] = (f32x4){0.f, 0.f, 0.f, 0.f};

    for (int k0 = 0; k0 < K; k0 += 32) {
        __syncthreads();
#pragma unroll
        for (int q = 0; q < 8; q++)
            __builtin_amdgcn_global_load_lds(
                (const __attribute__((address_space(1))) unsigned int*)(gsrc[q] + k0),
                (__attribute__((address_space(3))) unsigned int*)lds_dst[q], 16, 0, 0);
        __syncthreads();

        bf16x8 ah[4], al[4], bh[4], bl[4];
#pragma unroll
        for (int i = 0; i < 4; i++) {
            int ra = (quad * 128 + wr * 64 + i * 16 + l) * 8;
            ah[i] = *(const bf16x8*)&AsH[ra];
            al[i] = *(const bf16x8*)&AsL[ra];
            int rb2 = (quad * 128 + wc * 64 + i * 16 + l) * 8;
            bh[i] = *(const bf16x8*)&BsH[rb2];
            bl[i] = *(const bf16x8*)&BsL[rb2];
        }
#pragma unroll
        for (int i = 0; i < 4; i++)
#pragma unroll
            for (int j = 0; j < 4; j++) {
                acc[i][j] = __builtin_amdgcn_mfma_f32_16x16x32_bf16(ah[i], bh[j], acc[i][j], 0, 0, 0);
                acc[i][j] = __builtin_amdgcn_mfma_f32_16x16x32_bf16(al[i], bh[j], acc[i][j], 0, 0, 0);
                acc[i][j] = __builtin_amdgcn_mfma_f32_16x16x32_bf16(ah[i], bl[j], acc[i][j], 0, 0, 0);
            }
    }

    // ---- fused epilogue ----
    const int hcol = ((n0 + wc * 64) >> 6);   // head index 0..15
    if (z == 2) {
        // V: split + write directly in V^T tiled cell layout
#pragma unroll
        for (int i = 0; i < 4; i++)
#pragma unroll
            for (int r = 0; r < 4; r++) {
                int m = m0 + wr * 64 + i * 16 + quad * 4 + r;
                int bb = m >> 11, s = m & (Sc - 1);
                int T = s >> 6, tok = s & 63;
                size_t tilebase = (((size_t)(bb * Hc + hcol)) * 32 + T) * 4096;
#pragma unroll
                for (int j = 0; j < 4; j++) {
                    int d = j * 16 + l;
                    size_t off = tilebase + (size_t)((tok >> 3) * 64 + d) * 8 + (tok & 7);
                    unsigned short vh, vl;
                    split2(acc[i][j][r], vh, vl);
                    Vh[off] = vh;
                    Vl[off] = vl;
                }
            }
    } else {
#pragma unroll
        for (int i = 0; i < 4; i++)
#pragma unroll
            for (int r = 0; r < 4; r++) {
                int m = m0 + wr * 64 + i * 16 + quad * 4 + r;
                int bb = m >> 11, s = m & (Sc - 1);
#pragma unroll
                for (int jp = 0; jp < 2; jp++) {
                    int d = jp * 16 + l;                       // 0..31
                    float cs = ct[s * 32 + d];
                    float sn = st_[s * 32 + d];
                    float x0 = acc[i][jp][r];
                    float x1 = acc[i][jp + 2][r];
                    float y0 = x0 * cs - x1 * sn;
                    float y1 = x1 * cs + x0 * sn;
                    if (z == 0) {
                        y0 *= QSC; y1 *= QSC;
                        size_t rowb = (((size_t)(bb * Hc + hcol)) * Sc + s) * HDc;
                        unsigned short h_, l_;
                        split2(y0, h_, l_); Qh[rowb + d] = h_; Ql[rowb + d] = l_;
                        split2(y1, h_, l_); Qh[rowb + d + 32] = h_; Ql[rowb + d + 32] = l_;
                    } else {
                        int T = s >> 6, tok = s & 63;
                        size_t tb = (((size_t)(bb * Hc + hcol)) * 32 + T) * 8;
                        size_t off0 = ((tb + (d >> 3)) * 64 + tok) * 8 + (d & 7);
                        size_t off1 = ((tb + (d >> 3) + 4) * 64 + tok) * 8 + (d & 7);
                        unsigned short h_, l_;
                        split2(y0, h_, l_); Kh[off0] = h_; Kl[off0] = l_;
                        split2(y1, h_, l_); Kh[off1] = h_; Kl[off1] = l_;
                    }
                }
            }
    }
}

// ---------------------------------------------------------------------------
// MFMA flash attention v3: 128 q-rows/block (2 bands/wave), DMA-staged K/V,
// ones-column row sums (MFMA), DPP max-reduction, exp2-domain softmax.
// ---------------------------------------------------------------------------
__global__ __launch_bounds__(256) void attn3(
    const unsigned short* __restrict__ Qh, const unsigned short* __restrict__ Ql,
    const unsigned short* __restrict__ Kh, const unsigned short* __restrict__ Kl,
    const unsigned short* __restrict__ Vh, const unsigned short* __restrict__ Vl,
    unsigned short* __restrict__ AOh, unsigned short* __restrict__ AOl) {
    __shared__ __align__(16) unsigned short KsH[4096], KsL[4096], VtH[4096], VtL[4096];
    __shared__ __align__(16) unsigned short Ph[64 * 72], Pl[64 * 72];

    const int t = threadIdx.x;
    const int lane = t & 63;
    const int wave = t >> 6;
    const int l = lane & 15;
    const int quad = lane >> 4;
    // XCD-aware swizzle: consecutive-id blocks (round-robin across XCDs)
    // cluster 4 bh per XCD for K/V L2 locality.
    const int id = blockIdx.x;                 // 0..511
    const int bh = (id & 7) * 4 + (id >> 7);   // xcd*4 + hi bits
    const int qt = (id >> 3) & 15;
    const int q0 = qt * 128;
    const int b = bh >> 4;
    const int hh = bh & 15;

    const bf16x8 ONES = {(short)0x3F80, (short)0x3F80, (short)0x3F80, (short)0x3F80,
                         (short)0x3F80, (short)0x3F80, (short)0x3F80, (short)0x3F80};

    // Q fragments for both bands (pre-RoPE'd, pre-scaled by QSC, split)
    bf16x8 qfh[2][2], qfl[2][2];
#pragma unroll
    for (int bnd = 0; bnd < 2; bnd++) {
        size_t rowb = ((size_t)bh * Sc + q0 + bnd * 64 + wave * 16 + l) * HDc;
#pragma unroll
        for (int ks = 0; ks < 2; ks++) {
            qfh[bnd][ks] = *(const bf16x8*)(Qh + rowb + ks * 32 + quad * 8);
            qfl[bnd][ks] = *(const bf16x8*)(Ql + rowb + ks * 32 + quad * 8);
        }
    }

    f32x4 o[2][4], lac[2];
    float mrow[2][4];
#pragma unroll
    for (int bnd = 0; bnd < 2; bnd++) {
        lac[bnd] = (f32x4){0.f, 0.f, 0.f, 0.f};
#pragma unroll
        for (int i = 0; i < 4; i++) {
            o[bnd][i] = (f32x4){0.f, 0.f, 0.f, 0.f};
            mrow[bnd][i] = -INFINITY;
        }
    }

    const unsigned short* KhB = Kh + (size_t)bh * Sc * HDc;
    const unsigned short* KlB = Kl + (size_t)bh * Sc * HDc;
    const unsigned short* VhB = Vh + (size_t)bh * Sc * HDc;
    const unsigned short* VlB = Vl + (size_t)bh * Sc * HDc;

    for (int kt = 0; kt < 32; kt++) {
        __syncthreads();
        const size_t tb = (size_t)kt * 4096;
#pragma unroll
        for (int p = 0; p < 2; p++) {
            int c = wave * 2 + p;                  // chunk 0..7, 512 elems each
            int go = c * 512 + lane * 8;
            __builtin_amdgcn_global_load_lds(
                (const __attribute__((address_space(1))) unsigned int*)(KhB + tb + go),
                (__attribute__((address_space(3))) unsigned int*)&KsH[c * 512], 16, 0, 0);
            __builtin_amdgcn_global_load_lds(
                (const __attribute__((address_space(1))) unsigned int*)(KlB + tb + go),
                (__attribute__((address_space(3))) unsigned int*)&KsL[c * 512], 16, 0, 0);
            __builtin_amdgcn_global_load_lds(
                (const __attribute__((address_space(1))) unsigned int*)(VhB + tb + go),
                (__attribute__((address_space(3))) unsigned int*)&VtH[c * 512], 16, 0, 0);
            __builtin_amdgcn_global_load_lds(
                (const __attribute__((address_space(1))) unsigned int*)(VlB + tb + go),
                (__attribute__((address_space(3))) unsigned int*)&VtL[c * 512], 16, 0, 0);
        }
        __syncthreads();

        // ---- S = Q @ K^T for both bands; K frags read once ----
        f32x4 s[2][4];
#pragma unroll
        for (int bnd = 0; bnd < 2; bnd++)
#pragma unroll
            for (int tt = 0; tt < 4; tt++) s[bnd][tt] = (f32x4){0.f, 0.f, 0.f, 0.f};
#pragma unroll
        for (int ks = 0; ks < 2; ks++)
#pragma unroll
            for (int tt = 0; tt < 4; tt++) {
                const int off = ((ks * 4 + quad) * 64 + tt * 16 + l) * 8;
                bf16x8 kfh = *(const bf16x8*)&KsH[off];
                bf16x8 kfl = *(const bf16x8*)&KsL[off];
                s[0][tt] = __builtin_amdgcn_mfma_f32_16x16x32_bf16(qfh[0][ks], kfh, s[0][tt], 0, 0, 0);
                s[0][tt] = __builtin_amdgcn_mfma_f32_16x16x32_bf16(qfl[0][ks], kfh, s[0][tt], 0, 0, 0);
                s[0][tt] = __builtin_amdgcn_mfma_f32_16x16x32_bf16(qfh[0][ks], kfl, s[0][tt], 0, 0, 0);
                s[1][tt] = __builtin_amdgcn_mfma_f32_16x16x32_bf16(qfh[1][ks], kfh, s[1][tt], 0, 0, 0);
                s[1][tt] = __builtin_amdgcn_mfma_f32_16x16x32_bf16(qfl[1][ks], kfh, s[1][tt], 0, 0, 0);
                s[1][tt] = __builtin_amdgcn_mfma_f32_16x16x32_bf16(qfh[1][ks], kfl, s[1][tt], 0, 0, 0);
            }

        // ---- per-band: softmax -> P -> PV (P rows are wave-private) ----
#pragma unroll
        for (int bnd = 0; bnd < 2; bnd++) {
#pragma unroll
            for (int r = 0; r < 4; r++) {
                float mx = fmaxf(fmaxf(s[bnd][0][r], s[bnd][1][r]),
                                 fmaxf(s[bnd][2][r], s[bnd][3][r]));
                mx = maxdpp<0xB1>(mx);    // quad_perm [1,0,3,2]  (xor 1)
                mx = maxdpp<0x4E>(mx);    // quad_perm [2,3,0,1]  (xor 2)
                mx = maxdpp<0x141>(mx);   // row_half_mirror      (xor 4)
                mx = maxdpp<0x140>(mx);   // row_mirror           (xor 8)
                mx = fmaxf(mx, mrow[bnd][r]);
                float alpha = exp2f(mrow[bnd][r] - mx);
                mrow[bnd][r] = mx;
                const int prow = (wave * 16 + quad * 4 + r) * 72;
#pragma unroll
                for (int tt = 0; tt < 4; tt++) {
                    float p = exp2f(s[bnd][tt][r] - mx);
                    unsigned u = __float_as_uint(p);
                    float rem = p - __uint_as_float(u & 0xFFFF0000u);
                    Ph[prow + tt * 16 + l] = (unsigned short)(u >> 16);
                    Pl[prow + tt * 16 + l] = (unsigned short)(__float_as_uint(rem) >> 16);
                }
                lac[bnd][r] *= alpha;
                o[bnd][0][r] *= alpha;
                o[bnd][1][r] *= alpha;
                o[bnd][2][r] *= alpha;
                o[bnd][3][r] *= alpha;
            }
#pragma unroll
            for (int ks = 0; ks < 2; ks++) {
                const int poff = (wave * 16 + l) * 72 + ks * 32 + quad * 8;
                bf16x8 aph = *(const bf16x8*)&Ph[poff];
                bf16x8 apl = *(const bf16x8*)&Pl[poff];
                lac[bnd] = __builtin_amdgcn_mfma_f32_16x16x32_bf16(aph, ONES, lac[bnd], 0, 0, 0);
                lac[bnd] = __builtin_amdgcn_mfma_f32_16x16x32_bf16(apl, ONES, lac[bnd], 0, 0, 0);
#pragma unroll
                for (int tt = 0; tt < 4; tt++) {
                    const int off = ((ks * 4 + quad) * 64 + tt * 16 + l) * 8;
                    bf16x8 bvh = *(const bf16x8*)&VtH[off];
                    bf16x8 bvl = *(const bf16x8*)&VtL[off];
                    o[bnd][tt] = __builtin_amdgcn_mfma_f32_16x16x32_bf16(aph, bvh, o[bnd][tt], 0, 0, 0);
                    o[bnd][tt] = __builtin_amdgcn_mfma_f32_16x16x32_bf16(aph, bvl, o[bnd][tt], 0, 0, 0);
                    o[bnd][tt] = __builtin_amdgcn_mfma_f32_16x16x32_bf16(apl, bvh, o[bnd][tt], 0, 0, 0);
                }
            }
        }
    }

    // ---- epilogue: normalize + split to bf16 hi/lo [B,S,D] ----
#pragma unroll
    for (int bnd = 0; bnd < 2; bnd++)
#pragma unroll
        for (int r = 0; r < 4; r++) {
            float inv = 1.f / lac[bnd][r];
            int q = q0 + bnd * 64 + wave * 16 + quad * 4 + r;
            size_t rowb = ((size_t)b * Sc + q) * Dc + hh * HDc;
#pragma unroll
            for (int tt = 0; tt < 4; tt++) {
                unsigned short h_, l_;
                split2(o[bnd][tt][r] * inv, h_, l_);
                AOh[rowb + tt * 16 + l] = h_;
                AOl[rowb + tt * 16 + l] = l_;
            }
        }
}

// ---------------------------------------------------------------------------
// Output projection GEMM (MFMA split-bf16), fp32 store.
// ---------------------------------------------------------------------------
__global__ __launch_bounds__(256) void gemm_out(
    const unsigned short* __restrict__ Ah, const unsigned short* __restrict__ Al,
    const unsigned short* __restrict__ Wh, const unsigned short* __restrict__ Wl,
    float* __restrict__ C) {
    constexpr int K = 1024;
    __shared__ __align__(16) unsigned short AsH[4096], AsL[4096], BsH[4096], BsL[4096];

    const int t = threadIdx.x;
    const int lane = t & 63;
    const int wave = t >> 6;
    const int l = lane & 15;
    const int quad = lane >> 4;
    const int wr = wave >> 1, wc = wave & 1;
    const int m0 = blockIdx.y * 128;
    const int n0 = blockIdx.x * 128;

    const unsigned short* gsrc[8];
    const unsigned short* lds_dst[8];
#pragma unroll
    for (int q = 0; q < 8; q++) {
        int job = wave * 8 + q;
        int tensor = job >> 4;
        int half = (job >> 3) & 1;
        int rb = (job >> 2) & 1;
        int kb = job & 3;
        const unsigned short* g;
        const unsigned short* larr;
        int t0;
        if (tensor == 0) { g = half ? Al : Ah; larr = half ? AsL : AsH; t0 = m0; }
        else             { g = half ? Wl : Wh; larr = half ? BsL : BsH; t0 = n0; }
        gsrc[q] = g + (size_t)(t0 + rb * 64 + lane) * K + kb * 8;
        lds_dst[q] = larr + (kb * 128 + rb * 64) * 8;
    }

    f32x4 acc[4][4];
#pragma unroll
    for (int i = 0; i < 4; i++)
#pragma unroll
        for (int j = 0; j < 4; j++) acc[i][j] = (f32x4){0.f, 0.f, 0.f, 0.f};

    for (int k0 = 0; k0 < K; k0 += 32) {
        __syncthreads();
#pragma unroll
        for (int q = 0; q < 8; q++)
            __builtin_amdgcn_global_load_lds(
                (const __attribute__((address_space(1))) unsigned int*)(gsrc[q] + k0),
                (__attribute__((address_space(3))) unsigned int*)lds_dst[q], 16, 0, 0);
        __syncthreads();

        bf16x8 ah[4], al[4], bh[4], bl[4];
#pragma unroll
        for (int i = 0; i < 4; i++) {
            int ra = (quad * 128 + wr * 64 + i * 16 + l) * 8;
            ah[i] = *(const bf16x8*)&AsH[ra];
            al[i] = *(const bf16x8*)&AsL[ra];
            int rb2 = (quad * 128 + wc * 64 + i * 16 + l) * 8;
            bh[i] = *(const bf16x8*)&BsH[rb2];
            bl[i] = *(const bf16x8*)&BsL[rb2];
        }
#pragma unroll
        for (int i = 0; i < 4; i++)
#pragma unroll
            for (int j = 0; j < 4; j++) {
                acc[i][j] = __builtin_amdgcn_mfma_f32_16x16x32_bf16(ah[i], bh[j], acc[i][j], 0, 0, 0);
                acc[i][j] = __builtin_amdgcn_mfma_f32_16x16x32_bf16(al[i], bh[j], acc[i][j], 0, 0, 0);
                acc[i][j] = __builtin_amdgcn_mfma_f32_16x16x32_bf16(ah[i], bl[j], acc[i][j], 0, 0, 0);
            }
    }

#pragma unroll
    for (int i = 0; i < 4; i++)
#pragma unroll
        for (int j = 0; j < 4; j++)
#pragma unroll
            for (int r = 0; r < 4; r++) {
                int m = m0 + wr * 64 + i * 16 + quad * 4 + r;
                int n = n0 + wc * 64 + j * 16 + l;
                C[(size_t)m * Dc + n] = acc[i][j][r];
            }
}

// ---------------------------------------------------------------------------
extern "C" void kernel_launch(void* const* d_in, const int* in_sizes, int n_in,
                              void* d_out, int out_size, void* d_ws, size_t ws_size,
                              hipStream_t stream) {
    const float* x  = (const float*)d_in[0];
    const float* Wq = (const float*)d_in[1];
    const float* Wk = (const float*)d_in[2];
    const float* Wv = (const float*)d_in[3];
    const float* Wo = (const float*)d_in[4];
    float* out = (float*)d_out;

    unsigned short* usw = (unsigned short*)d_ws;
    const size_t M4 = (size_t)1 << 22;   // 4M elements
    unsigned short* whAll = usw;                 // 4 x 1M weights hi
    unsigned short* wlAll = usw + M4;            // lo
    unsigned short* xh = usw + 2 * M4;           // x hi  (later AOh)
    unsigned short* xl = usw + 3 * M4;           // x lo  (later AOl)
    unsigned short* Qh = usw + 4 * M4;
    unsigned short* Ql = usw + 5 * M4;
    unsigned short* Kh = usw + 6 * M4;
    unsigned short* Kl = usw + 7 * M4;
    unsigned short* Vh = usw + 8 * M4;
    unsigned short* Vl = usw + 9 * M4;
    float* ct = (float*)(usw + 10 * M4);
    float* st_ = ct + (size_t)Sc * 32;
    unsigned short* AOh = xh;   // x dead after QKV GEMM
    unsigned short* AOl = xl;

    // 1. RoPE table
    rope_table<<<dim3((Sc * 32) / 256), dim3(256), 0, stream>>>(ct, st_);
    // 2. split x + weights to bf16 hi/lo
    split_xw<<<dim3(4096, 5), dim3(256), 0, stream>>>(x, Wq, Wk, Wv, Wo, xh, xl, whAll, wlAll);
    // 3. QKV projections with fused RoPE/scale/split/V^T epilogues
    gemm_qkv<<<dim3(8, 32, 3), dim3(256), 0, stream>>>(
        xh, xl, whAll, wlAll, Qh, Ql, Kh, Kl, Vh, Vl, ct, st_);
    // 4. attention (DMA-staged, 128 q/block) -> AOh/AOl bf16 hi/lo
    attn3<<<dim3(512), dim3(256), 0, stream>>>(
        Qh, Ql, Kh, Kl, Vh, Vl, AOh, AOl);
    // 5. output projection
    gemm_out<<<dim3(8, 32), dim3(256), 0, stream>>>(
        AOh, AOl, whAll + 3 * (1 << 20), wlAll + 3 * (1 << 20), out);
}

// Round 6
// 391.589 us; speedup vs baseline: 4.7546x; 1.1687x over previous
//
#include <hip/hip_runtime.h>
#include <math.h>

// Problem constants
constexpr int Bc = 2;
constexpr int Sc = 2048;
constexpr int Dc = 1024;
constexpr int Hc = 16;
constexpr int HDc = 64;

// Q pre-scale: attention 1/sqrt(64) folded with log2(e) for exp2-domain softmax
constexpr float QSC = 0.125f * 1.4426950408889634f;

typedef __attribute__((ext_vector_type(8))) short bf16x8;
typedef __attribute__((ext_vector_type(4))) float f32x4;
typedef __attribute__((ext_vector_type(4))) unsigned short us4;

// fp32 -> bf16 round-to-nearest-even (returns low 16 bits)
__device__ __forceinline__ unsigned f2bf(float x) {
    unsigned u = __float_as_uint(x);
    return (u + 0x7FFFu + ((u >> 16) & 1u)) >> 16;
}

__device__ __forceinline__ void split2(float x, unsigned short& h, unsigned short& l) {
    unsigned hh = f2bf(x);
    h = (unsigned short)hh;
    l = (unsigned short)f2bf(x - __uint_as_float(hh << 16));
}

// ---------------------------------------------------------------------------
// RoPE cos/sin table: [S][32] each, double precision angles.
// ---------------------------------------------------------------------------
__global__ void rope_table(float* __restrict__ ct, float* __restrict__ st_) {
    int id = blockIdx.x * 256 + threadIdx.x;
    int s = id >> 5;
    int i = id & 31;
    double invf = pow(10000.0, -(double)i / 32.0);
    double ang = (double)s * invf;
    ct[id] = (float)cos(ang);
    st_[id] = (float)sin(ang);
}

// ---------------------------------------------------------------------------
// Split fp32 -> bf16 hi/lo.  y=0: x (4M elems); y=1..4: W_{q,k,v,o} (1M each).
// ---------------------------------------------------------------------------
__global__ void split_xw(const float* __restrict__ x,
                         const float* __restrict__ Wq, const float* __restrict__ Wk,
                         const float* __restrict__ Wv, const float* __restrict__ Wo,
                         unsigned short* __restrict__ xh, unsigned short* __restrict__ xl,
                         unsigned short* __restrict__ whAll, unsigned short* __restrict__ wlAll) {
    int y = blockIdx.y;
    const float* src;
    unsigned short *h, *l;
    int n;
    if (y == 0) { src = x; h = xh; l = xl; n = 1 << 22; }
    else {
        src = (y == 1) ? Wq : (y == 2) ? Wk : (y == 3) ? Wv : Wo;
        h = whAll + (size_t)(y - 1) * (1 << 20);
        l = wlAll + (size_t)(y - 1) * (1 << 20);
        n = 1 << 20;
    }
    int i = (blockIdx.x * 256 + threadIdx.x) * 4;
    if (i >= n) return;
    float4 v = *(const float4*)(src + i);
    us4 hh, ll;
    split2(v.x, ((unsigned short*)&hh)[0], ((unsigned short*)&ll)[0]);
    split2(v.y, ((unsigned short*)&hh)[1], ((unsigned short*)&ll)[1]);
    split2(v.z, ((unsigned short*)&hh)[2], ((unsigned short*)&ll)[2]);
    split2(v.w, ((unsigned short*)&hh)[3], ((unsigned short*)&ll)[3]);
    *(us4*)(h + i) = hh;
    *(us4*)(l + i) = ll;
}

// ---------------------------------------------------------------------------
// QKV GEMM (MFMA split-bf16, 3-product), 128x128 tile, BK=32, 4 waves.
// Fused epilogue: z=0 -> RoPE + QSC scale Q -> Qh/Ql row-major [bh][s][64]
//                 z=1 -> RoPE K  -> Kh/Kl tiled cells [bh][T][kb][tok][8]
//                 z=2 -> V (rte bf16, single) -> Vh V^T cells [bh][T][kkb][d][kk]
// ---------------------------------------------------------------------------
__global__ __launch_bounds__(256) void gemm_qkv(
    const unsigned short* __restrict__ Ah, const unsigned short* __restrict__ Al,
    const unsigned short* __restrict__ whAll, const unsigned short* __restrict__ wlAll,
    unsigned short* __restrict__ Qh, unsigned short* __restrict__ Ql,
    unsigned short* __restrict__ Kh, unsigned short* __restrict__ Kl,
    unsigned short* __restrict__ Vh,
    const float* __restrict__ ct, const float* __restrict__ st_) {
    constexpr int K = 1024;
    __shared__ __align__(16) unsigned short AsH[4096], AsL[4096], BsH[4096], BsL[4096];

    const int z = blockIdx.z;
    const unsigned short* Wh = whAll + (size_t)z * (1 << 20);
    const unsigned short* Wl = wlAll + (size_t)z * (1 << 20);

    const int t = threadIdx.x;
    const int lane = t & 63;
    const int wave = t >> 6;
    const int l = lane & 15;
    const int quad = lane >> 4;
    const int wr = wave >> 1, wc = wave & 1;
    const int m0 = blockIdx.y * 128;
    const int n0 = blockIdx.x * 128;

    const unsigned short* gsrc[8];
    const unsigned short* lds_dst[8];
#pragma unroll
    for (int q = 0; q < 8; q++) {
        int job = wave * 8 + q;
        int tensor = job >> 4;
        int half = (job >> 3) & 1;
        int rb = (job >> 2) & 1;
        int kb = job & 3;
        const unsigned short* g;
        const unsigned short* larr;
        int t0;
        if (tensor == 0) { g = half ? Al : Ah; larr = half ? AsL : AsH; t0 = m0; }
        else             { g = half ? Wl : Wh; larr = half ? BsL : BsH; t0 = n0; }
        gsrc[q] = g + (size_t)(t0 + rb * 64 + lane) * K + kb * 8;
        lds_dst[q] = larr + (kb * 128 + rb * 64) * 8;
    }

    f32x4 acc[4][4];
#pragma unroll
    for (int i = 0; i < 4; i++)
#pragma unroll
        for (int j = 0; j < 4; j++) acc[i][j] = (f32x4){0.f, 0.f, 0.f, 0.f};

    for (int k0 = 0; k0 < K; k0 += 32) {
        __syncthreads();
#pragma unroll
        for (int q = 0; q < 8; q++)
            __builtin_amdgcn_global_load_lds(
                (const __attribute__((address_space(1))) unsigned int*)(gsrc[q] + k0),
                (__attribute__((address_space(3))) unsigned int*)lds_dst[q], 16, 0, 0);
        __syncthreads();

        bf16x8 ah[4], al[4], bh[4], bl[4];
#pragma unroll
        for (int i = 0; i < 4; i++) {
            int ra = (quad * 128 + wr * 64 + i * 16 + l) * 8;
            ah[i] = *(const bf16x8*)&AsH[ra];
            al[i] = *(const bf16x8*)&AsL[ra];
            int rb2 = (quad * 128 + wc * 64 + i * 16 + l) * 8;
            bh[i] = *(const bf16x8*)&BsH[rb2];
            bl[i] = *(const bf16x8*)&BsL[rb2];
        }
#pragma unroll
        for (int i = 0; i < 4; i++)
#pragma unroll
            for (int j = 0; j < 4; j++) {
                acc[i][j] = __builtin_amdgcn_mfma_f32_16x16x32_bf16(ah[i], bh[j], acc[i][j], 0, 0, 0);
                acc[i][j] = __builtin_amdgcn_mfma_f32_16x16x32_bf16(al[i], bh[j], acc[i][j], 0, 0, 0);
                acc[i][j] = __builtin_amdgcn_mfma_f32_16x16x32_bf16(ah[i], bl[j], acc[i][j], 0, 0, 0);
            }
    }

    // ---- fused epilogue ----
    const int hcol = ((n0 + wc * 64) >> 6);   // head index 0..15
    if (z == 2) {
        // V: single rte bf16, V^T tiled cell layout
#pragma unroll
        for (int i = 0; i < 4; i++)
#pragma unroll
            for (int r = 0; r < 4; r++) {
                int m = m0 + wr * 64 + i * 16 + quad * 4 + r;
                int bb = m >> 11, s = m & (Sc - 1);
                int T = s >> 6, tok = s & 63;
                size_t tilebase = (((size_t)(bb * Hc + hcol)) * 32 + T) * 4096;
#pragma unroll
                for (int j = 0; j < 4; j++) {
                    int d = j * 16 + l;
                    size_t off = tilebase + (size_t)((tok >> 3) * 64 + d) * 8 + (tok & 7);
                    Vh[off] = (unsigned short)f2bf(acc[i][j][r]);
                }
            }
    } else {
#pragma unroll
        for (int i = 0; i < 4; i++)
#pragma unroll
            for (int r = 0; r < 4; r++) {
                int m = m0 + wr * 64 + i * 16 + quad * 4 + r;
                int bb = m >> 11, s = m & (Sc - 1);
#pragma unroll
                for (int jp = 0; jp < 2; jp++) {
                    int d = jp * 16 + l;                       // 0..31
                    float cs = ct[s * 32 + d];
                    float sn = st_[s * 32 + d];
                    float x0 = acc[i][jp][r];
                    float x1 = acc[i][jp + 2][r];
                    float y0 = x0 * cs - x1 * sn;
                    float y1 = x1 * cs + x0 * sn;
                    if (z == 0) {
                        y0 *= QSC; y1 *= QSC;
                        size_t rowb = (((size_t)(bb * Hc + hcol)) * Sc + s) * HDc;
                        unsigned short h_, l_;
                        split2(y0, h_, l_); Qh[rowb + d] = h_; Ql[rowb + d] = l_;
                        split2(y1, h_, l_); Qh[rowb + d + 32] = h_; Ql[rowb + d + 32] = l_;
                    } else {
                        int T = s >> 6, tok = s & 63;
                        size_t tb = (((size_t)(bb * Hc + hcol)) * 32 + T) * 8;
                        size_t off0 = ((tb + (d >> 3)) * 64 + tok) * 8 + (d & 7);
                        size_t off1 = ((tb + (d >> 3) + 4) * 64 + tok) * 8 + (d & 7);
                        unsigned short h_, l_;
                        split2(y0, h_, l_); Kh[off0] = h_; Kl[off0] = l_;
                        split2(y1, h_, l_); Kh[off1] = h_; Kl[off1] = l_;
                    }
                }
            }
    }
}

// ---------------------------------------------------------------------------
// MFMA flash attention v4: no-rescale softmax (scores can't overflow fp32),
// P single trunc-bf16 (first-order error cancels via shared lac), V single
// rte-bf16, V/P fragments shared across both bands.
// ---------------------------------------------------------------------------
__global__ __launch_bounds__(256) void attn4(
    const unsigned short* __restrict__ Qh, const unsigned short* __restrict__ Ql,
    const unsigned short* __restrict__ Kh, const unsigned short* __restrict__ Kl,
    const unsigned short* __restrict__ Vh,
    unsigned short* __restrict__ AOh, unsigned short* __restrict__ AOl) {
    __shared__ __align__(16) unsigned short KsH[4096], KsL[4096], VtH[4096];
    __shared__ __align__(16) unsigned short Ph[128 * 72];

    const int t = threadIdx.x;
    const int lane = t & 63;
    const int wave = t >> 6;
    const int l = lane & 15;
    const int quad = lane >> 4;
    // XCD-aware swizzle: cluster 4 bh per XCD for K/V L2 locality.
    const int id = blockIdx.x;                 // 0..511
    const int bh = (id & 7) * 4 + (id >> 7);
    const int qt = (id >> 3) & 15;
    const int q0 = qt * 128;
    const int b = bh >> 4;
    const int hh = bh & 15;

    const bf16x8 ONES = {(short)0x3F80, (short)0x3F80, (short)0x3F80, (short)0x3F80,
                         (short)0x3F80, (short)0x3F80, (short)0x3F80, (short)0x3F80};

    // Q fragments for both bands (pre-RoPE'd, pre-scaled by QSC, split)
    bf16x8 qfh[2][2], qfl[2][2];
#pragma unroll
    for (int bnd = 0; bnd < 2; bnd++) {
        size_t rowb = ((size_t)bh * Sc + q0 + bnd * 64 + wave * 16 + l) * HDc;
#pragma unroll
        for (int ks = 0; ks < 2; ks++) {
            qfh[bnd][ks] = *(const bf16x8*)(Qh + rowb + ks * 32 + quad * 8);
            qfl[bnd][ks] = *(const bf16x8*)(Ql + rowb + ks * 32 + quad * 8);
        }
    }

    f32x4 o[2][4], lac[2];
#pragma unroll
    for (int bnd = 0; bnd < 2; bnd++) {
        lac[bnd] = (f32x4){0.f, 0.f, 0.f, 0.f};
#pragma unroll
        for (int i = 0; i < 4; i++) o[bnd][i] = (f32x4){0.f, 0.f, 0.f, 0.f};
    }

    const unsigned short* KhB = Kh + (size_t)bh * Sc * HDc;
    const unsigned short* KlB = Kl + (size_t)bh * Sc * HDc;
    const unsigned short* VhB = Vh + (size_t)bh * Sc * HDc;

    for (int kt = 0; kt < 32; kt++) {
        __syncthreads();
        const size_t tb = (size_t)kt * 4096;
#pragma unroll
        for (int p = 0; p < 2; p++) {
            int c = wave * 2 + p;                  // chunk 0..7, 512 elems each
            int go = c * 512 + lane * 8;
            __builtin_amdgcn_global_load_lds(
                (const __attribute__((address_space(1))) unsigned int*)(KhB + tb + go),
                (__attribute__((address_space(3))) unsigned int*)&KsH[c * 512], 16, 0, 0);
            __builtin_amdgcn_global_load_lds(
                (const __attribute__((address_space(1))) unsigned int*)(KlB + tb + go),
                (__attribute__((address_space(3))) unsigned int*)&KsL[c * 512], 16, 0, 0);
            __builtin_amdgcn_global_load_lds(
                (const __attribute__((address_space(1))) unsigned int*)(VhB + tb + go),
                (__attribute__((address_space(3))) unsigned int*)&VtH[c * 512], 16, 0, 0);
        }
        __syncthreads();

        // ---- S = Q @ K^T for both bands; K frags read once ----
        f32x4 s[2][4];
#pragma unroll
        for (int bnd = 0; bnd < 2; bnd++)
#pragma unroll
            for (int tt = 0; tt < 4; tt++) s[bnd][tt] = (f32x4){0.f, 0.f, 0.f, 0.f};
#pragma unroll
        for (int ks = 0; ks < 2; ks++)
#pragma unroll
            for (int tt = 0; tt < 4; tt++) {
                const int off = ((ks * 4 + quad) * 64 + tt * 16 + l) * 8;
                bf16x8 kfh = *(const bf16x8*)&KsH[off];
                bf16x8 kfl = *(const bf16x8*)&KsL[off];
                s[0][tt] = __builtin_amdgcn_mfma_f32_16x16x32_bf16(qfh[0][ks], kfh, s[0][tt], 0, 0, 0);
                s[0][tt] = __builtin_amdgcn_mfma_f32_16x16x32_bf16(qfl[0][ks], kfh, s[0][tt], 0, 0, 0);
                s[0][tt] = __builtin_amdgcn_mfma_f32_16x16x32_bf16(qfh[0][ks], kfl, s[0][tt], 0, 0, 0);
                s[1][tt] = __builtin_amdgcn_mfma_f32_16x16x32_bf16(qfh[1][ks], kfh, s[1][tt], 0, 0, 0);
                s[1][tt] = __builtin_amdgcn_mfma_f32_16x16x32_bf16(qfl[1][ks], kfh, s[1][tt], 0, 0, 0);
                s[1][tt] = __builtin_amdgcn_mfma_f32_16x16x32_bf16(qfh[1][ks], kfl, s[1][tt], 0, 0, 0);
            }

        // ---- P = exp2(S), trunc-bf16, no rescale ----
#pragma unroll
        for (int bnd = 0; bnd < 2; bnd++)
#pragma unroll
            for (int r = 0; r < 4; r++) {
                const int prow = (bnd * 64 + wave * 16 + quad * 4 + r) * 72;
#pragma unroll
                for (int tt = 0; tt < 4; tt++) {
                    float p = exp2f(s[bnd][tt][r]);
                    Ph[prow + tt * 16 + l] = (unsigned short)(__float_as_uint(p) >> 16);
                }
            }

        // ---- O += P @ V, l += P @ 1; V frags shared across bands ----
#pragma unroll
        for (int ks = 0; ks < 2; ks++) {
            const int p0 = (wave * 16 + l) * 72 + ks * 32 + quad * 8;
            bf16x8 aph0 = *(const bf16x8*)&Ph[p0];
            bf16x8 aph1 = *(const bf16x8*)&Ph[p0 + 64 * 72];
            lac[0] = __builtin_amdgcn_mfma_f32_16x16x32_bf16(aph0, ONES, lac[0], 0, 0, 0);
            lac[1] = __builtin_amdgcn_mfma_f32_16x16x32_bf16(aph1, ONES, lac[1], 0, 0, 0);
#pragma unroll
            for (int tt = 0; tt < 4; tt++) {
                const int off = ((ks * 4 + quad) * 64 + tt * 16 + l) * 8;
                bf16x8 bvh = *(const bf16x8*)&VtH[off];
                o[0][tt] = __builtin_amdgcn_mfma_f32_16x16x32_bf16(aph0, bvh, o[0][tt], 0, 0, 0);
                o[1][tt] = __builtin_amdgcn_mfma_f32_16x16x32_bf16(aph1, bvh, o[1][tt], 0, 0, 0);
            }
        }
    }

    // ---- epilogue: normalize + split to bf16 hi/lo [B,S,D] ----
#pragma unroll
    for (int bnd = 0; bnd < 2; bnd++)
#pragma unroll
        for (int r = 0; r < 4; r++) {
            float inv = 1.f / lac[bnd][r];
            int q = q0 + bnd * 64 + wave * 16 + quad * 4 + r;
            size_t rowb = ((size_t)b * Sc + q) * Dc + hh * HDc;
#pragma unroll
            for (int tt = 0; tt < 4; tt++) {
                unsigned short h_, l_;
                split2(o[bnd][tt][r] * inv, h_, l_);
                AOh[rowb + tt * 16 + l] = h_;
                AOl[rowb + tt * 16 + l] = l_;
            }
        }
}

// ---------------------------------------------------------------------------
// Output projection GEMM (MFMA split-bf16), fp32 store.
// ---------------------------------------------------------------------------
__global__ __launch_bounds__(256) void gemm_out(
    const unsigned short* __restrict__ Ah, const unsigned short* __restrict__ Al,
    const unsigned short* __restrict__ Wh, const unsigned short* __restrict__ Wl,
    float* __restrict__ C) {
    constexpr int K = 1024;
    __shared__ __align__(16) unsigned short AsH[4096], AsL[4096], BsH[4096], BsL[4096];

    const int t = threadIdx.x;
    const int lane = t & 63;
    const int wave = t >> 6;
    const int l = lane & 15;
    const int quad = lane >> 4;
    const int wr = wave >> 1, wc = wave & 1;
    const int m0 = blockIdx.y * 128;
    const int n0 = blockIdx.x * 128;

    const unsigned short* gsrc[8];
    const unsigned short* lds_dst[8];
#pragma unroll
    for (int q = 0; q < 8; q++) {
        int job = wave * 8 + q;
        int tensor = job >> 4;
        int half = (job >> 3) & 1;
        int rb = (job >> 2) & 1;
        int kb = job & 3;
        const unsigned short* g;
        const unsigned short* larr;
        int t0;
        if (tensor == 0) { g = half ? Al : Ah; larr = half ? AsL : AsH; t0 = m0; }
        else             { g = half ? Wl : Wh; larr = half ? BsL : BsH; t0 = n0; }
        gsrc[q] = g + (size_t)(t0 + rb * 64 + lane) * K + kb * 8;
        lds_dst[q] = larr + (kb * 128 + rb * 64) * 8;
    }

    f32x4 acc[4][4];
#pragma unroll
    for (int i = 0; i < 4; i++)
#pragma unroll
        for (int j = 0; j < 4; j++) acc[i][j] = (f32x4){0.f, 0.f, 0.f, 0.f};

    for (int k0 = 0; k0 < K; k0 += 32) {
        __syncthreads();
#pragma unroll
        for (int q = 0; q < 8; q++)
            __builtin_amdgcn_global_load_lds(
                (const __attribute__((address_space(1))) unsigned int*)(gsrc[q] + k0),
                (__attribute__((address_space(3))) unsigned int*)lds_dst[q], 16, 0, 0);
        __syncthreads();

        bf16x8 ah[4], al[4], bh[4], bl[4];
#pragma unroll
        for (int i = 0; i < 4; i++) {
            int ra = (quad * 128 + wr * 64 + i * 16 + l) * 8;
            ah[i] = *(const bf16x8*)&AsH[ra];
            al[i] = *(const bf16x8*)&AsL[ra];
            int rb2 = (quad * 128 + wc * 64 + i * 16 + l) * 8;
            bh[i] = *(const bf16x8*)&BsH[rb2];
            bl[i] = *(const bf16x8*)&BsL[rb2];
        }
#pragma unroll
        for (int i = 0; i < 4; i++)
#pragma unroll
            for (int j = 0; j < 4; j++) {
                acc[i][j] = __builtin_amdgcn_mfma_f32_16x16x32_bf16(ah[i], bh[j], acc[i][j], 0, 0, 0);
                acc[i][j] = __builtin_amdgcn_mfma_f32_16x16x32_bf16(al[i], bh[j], acc[i][j], 0, 0, 0);
                acc[i][j] = __builtin_amdgcn_mfma_f32_16x16x32_bf16(ah[i], bl[j], acc[i][j], 0, 0, 0);
            }
    }

#pragma unroll
    for (int i = 0; i < 4; i++)
#pragma unroll
        for (int j = 0; j < 4; j++)
#pragma unroll
            for (int r = 0; r < 4; r++) {
                int m = m0 + wr * 64 + i * 16 + quad * 4 + r;
                int n = n0 + wc * 64 + j * 16 + l;
                C[(size_t)m * Dc + n] = acc[i][j][r];
            }
}

// ---------------------------------------------------------------------------
extern "C" void kernel_launch(void* const* d_in, const int* in_sizes, int n_in,
                              void* d_out, int out_size, void* d_ws, size_t ws_size,
                              hipStream_t stream) {
    const float* x  = (const float*)d_in[0];
    const float* Wq = (const float*)d_in[1];
    const float* Wk = (const float*)d_in[2];
    const float* Wv = (const float*)d_in[3];
    const float* Wo = (const float*)d_in[4];
    float* out = (float*)d_out;

    unsigned short* usw = (unsigned short*)d_ws;
    const size_t M4 = (size_t)1 << 22;   // 4M elements
    unsigned short* whAll = usw;                 // 4 x 1M weights hi
    unsigned short* wlAll = usw + M4;            // lo
    unsigned short* xh = usw + 2 * M4;           // x hi  (later AOh)
    unsigned short* xl = usw + 3 * M4;           // x lo  (later AOl)
    unsigned short* Qh = usw + 4 * M4;
    unsigned short* Ql = usw + 5 * M4;
    unsigned short* Kh = usw + 6 * M4;
    unsigned short* Kl = usw + 7 * M4;
    unsigned short* Vh = usw + 8 * M4;
    float* ct = (float*)(usw + 10 * M4);
    float* st_ = ct + (size_t)Sc * 32;
    unsigned short* AOh = xh;   // x dead after QKV GEMM
    unsigned short* AOl = xl;

    // 1. RoPE table
    rope_table<<<dim3((Sc * 32) / 256), dim3(256), 0, stream>>>(ct, st_);
    // 2. split x + weights to bf16 hi/lo
    split_xw<<<dim3(4096, 5), dim3(256), 0, stream>>>(x, Wq, Wk, Wv, Wo, xh, xl, whAll, wlAll);
    // 3. QKV projections with fused RoPE/scale/split/V^T epilogues
    gemm_qkv<<<dim3(8, 32, 3), dim3(256), 0, stream>>>(
        xh, xl, whAll, wlAll, Qh, Ql, Kh, Kl, Vh, ct, st_);
    // 4. attention (no-rescale, DMA-staged, 128 q/block) -> AOh/AOl
    attn4<<<dim3(512), dim3(256), 0, stream>>>(
        Qh, Ql, Kh, Kl, Vh, AOh, AOl);
    // 5. output projection
    gemm_out<<<dim3(8, 32), dim3(256), 0, stream>>>(
        AOh, AOl, whAll + 3 * (1 << 20), wlAll + 3 * (1 << 20), out);
}

// Round 7
// 265.135 us; speedup vs baseline: 7.0222x; 1.4769x over previous
//
#include <hip/hip_runtime.h>
#include <math.h>

// Problem constants
constexpr int Bc = 2;
constexpr int Sc = 2048;
constexpr int Dc = 1024;
constexpr int Hc = 16;
constexpr int HDc = 64;

// Q pre-scale: attention 1/sqrt(64) folded with log2(e) for exp2-domain softmax
constexpr float QSC = 0.125f * 1.4426950408889634f;

typedef __attribute__((ext_vector_type(8))) short bf16x8;
typedef __attribute__((ext_vector_type(4))) float f32x4;
typedef __attribute__((ext_vector_type(4))) unsigned short us4;

// fp32 -> bf16 round-to-nearest-even (returns low 16 bits)
__device__ __forceinline__ unsigned f2bf(float x) {
    unsigned u = __float_as_uint(x);
    return (u + 0x7FFFu + ((u >> 16) & 1u)) >> 16;
}

__device__ __forceinline__ void split2(float x, unsigned short& h, unsigned short& l) {
    unsigned hh = f2bf(x);
    h = (unsigned short)hh;
    l = (unsigned short)f2bf(x - __uint_as_float(hh << 16));
}

// ---------------------------------------------------------------------------
// RoPE cos/sin table: [S][32] each, double precision angles.
// ---------------------------------------------------------------------------
__global__ void rope_table(float* __restrict__ ct, float* __restrict__ st_) {
    int id = blockIdx.x * 256 + threadIdx.x;
    int s = id >> 5;
    int i = id & 31;
    double invf = pow(10000.0, -(double)i / 32.0);
    double ang = (double)s * invf;
    ct[id] = (float)cos(ang);
    st_[id] = (float)sin(ang);
}

// ---------------------------------------------------------------------------
// Convert: x -> bf16 hi only; Wq/Wk/Wv -> hi only; Wo -> hi + lo (3-product
// fidelity kept only in the out-projection).
// ---------------------------------------------------------------------------
__global__ void split_xw(const float* __restrict__ x,
                         const float* __restrict__ Wq, const float* __restrict__ Wk,
                         const float* __restrict__ Wv, const float* __restrict__ Wo,
                         unsigned short* __restrict__ xh,
                         unsigned short* __restrict__ whAll, unsigned short* __restrict__ wlAll) {
    int y = blockIdx.y;
    const float* src;
    unsigned short* h;
    unsigned short* l = nullptr;
    int n;
    if (y == 0) { src = x; h = xh; n = 1 << 22; }
    else {
        src = (y == 1) ? Wq : (y == 2) ? Wk : (y == 3) ? Wv : Wo;
        h = whAll + (size_t)(y - 1) * (1 << 20);
        if (y == 4) l = wlAll + (size_t)3 * (1 << 20);
        n = 1 << 20;
    }
    int i = (blockIdx.x * 256 + threadIdx.x) * 4;
    if (i >= n) return;
    float4 v = *(const float4*)(src + i);
    us4 hh;
    ((unsigned short*)&hh)[0] = (unsigned short)f2bf(v.x);
    ((unsigned short*)&hh)[1] = (unsigned short)f2bf(v.y);
    ((unsigned short*)&hh)[2] = (unsigned short)f2bf(v.z);
    ((unsigned short*)&hh)[3] = (unsigned short)f2bf(v.w);
    *(us4*)(h + i) = hh;
    if (l) {
        us4 ll;
        const float* vp = (const float*)&v;
#pragma unroll
        for (int e = 0; e < 4; e++) {
            unsigned short hi = ((unsigned short*)&hh)[e];
            ((unsigned short*)&ll)[e] =
                (unsigned short)f2bf(vp[e] - __uint_as_float((unsigned)hi << 16));
        }
        *(us4*)(l + i) = ll;
    }
}

// ---------------------------------------------------------------------------
// QKV GEMM, plain bf16 1-product, 128x128 tile, BK=32, LDS double-buffered
// (single barrier per k-iter; prefetch overlaps compute). m-fastest grid:
// XCD = m&7 -> per-XCD A footprint 1 MB (L2-resident, no HBM re-fetch).
// Fused epilogue: z=0 Q (RoPE+QSC, bf16), z=1 K (RoPE, tiled cells),
//                 z=2 V (V^T tiled cells).
// ---------------------------------------------------------------------------
__global__ __launch_bounds__(256) void gemm_qkv(
    const unsigned short* __restrict__ Ah,
    const unsigned short* __restrict__ whAll,
    unsigned short* __restrict__ Qh,
    unsigned short* __restrict__ Kh,
    unsigned short* __restrict__ Vh,
    const float* __restrict__ ct, const float* __restrict__ st_) {
    constexpr int K = 1024;
    __shared__ __align__(16) unsigned short AsH[2 * 4096], BsH[2 * 4096];

    const int z = blockIdx.z;
    const unsigned short* Wh = whAll + (size_t)z * (1 << 20);

    const int t = threadIdx.x;
    const int lane = t & 63;
    const int wave = t >> 6;
    const int l = lane & 15;
    const int quad = lane >> 4;
    const int wr = wave >> 1, wc = wave & 1;
    const int m0 = blockIdx.x * 128;   // m fastest -> XCD A-locality
    const int n0 = blockIdx.y * 128;

    // staging: wave = (tensor<<1)|rowblock, q = kb cell. 16 KB per k-iter.
    const int s_tensor = wave >> 1;
    const int s_rb = wave & 1;
    unsigned short* larr = s_tensor ? BsH : AsH;
    const unsigned short* gbase =
        (s_tensor ? Wh + (size_t)(n0 + s_rb * 64 + lane) * K
                  : Ah + (size_t)(m0 + s_rb * 64 + lane) * K);

    f32x4 acc[4][4];
#pragma unroll
    for (int i = 0; i < 4; i++)
#pragma unroll
        for (int j = 0; j < 4; j++) acc[i][j] = (f32x4){0.f, 0.f, 0.f, 0.f};

    // preload k-iter 0 into buffer 0
#pragma unroll
    for (int q = 0; q < 4; q++)
        __builtin_amdgcn_global_load_lds(
            (const __attribute__((address_space(1))) unsigned int*)(gbase + q * 8),
            (__attribute__((address_space(3))) unsigned int*)(larr + (q * 128 + s_rb * 64) * 8),
            16, 0, 0);

    for (int it = 0; it < 32; ++it) {
        __syncthreads();   // drains DMA for buf[it&1]; fences prev compute
        if (it + 1 < 32) {
            const unsigned short* g = gbase + (it + 1) * 32;
            unsigned short* buf = larr + ((it + 1) & 1) * 4096;
#pragma unroll
            for (int q = 0; q < 4; q++)
                __builtin_amdgcn_global_load_lds(
                    (const __attribute__((address_space(1))) unsigned int*)(g + q * 8),
                    (__attribute__((address_space(3))) unsigned int*)(buf + (q * 128 + s_rb * 64) * 8),
                    16, 0, 0);
        }
        const unsigned short* a = AsH + (it & 1) * 4096;
        const unsigned short* bb = BsH + (it & 1) * 4096;
        bf16x8 ah[4], bh[4];
#pragma unroll
        for (int i = 0; i < 4; i++) {
            ah[i] = *(const bf16x8*)&a[(quad * 128 + wr * 64 + i * 16 + l) * 8];
            bh[i] = *(const bf16x8*)&bb[(quad * 128 + wc * 64 + i * 16 + l) * 8];
        }
#pragma unroll
        for (int i = 0; i < 4; i++)
#pragma unroll
            for (int j = 0; j < 4; j++)
                acc[i][j] = __builtin_amdgcn_mfma_f32_16x16x32_bf16(ah[i], bh[j], acc[i][j], 0, 0, 0);
    }

    // ---- fused epilogue (single bf16 outputs) ----
    const int hcol = ((n0 + wc * 64) >> 6);   // head index 0..15
    if (z == 2) {
#pragma unroll
        for (int i = 0; i < 4; i++)
#pragma unroll
            for (int r = 0; r < 4; r++) {
                int m = m0 + wr * 64 + i * 16 + quad * 4 + r;
                int bbk = m >> 11, s = m & (Sc - 1);
                int T = s >> 6, tok = s & 63;
                size_t tilebase = (((size_t)(bbk * Hc + hcol)) * 32 + T) * 4096;
#pragma unroll
                for (int j = 0; j < 4; j++) {
                    int d = j * 16 + l;
                    size_t off = tilebase + (size_t)((tok >> 3) * 64 + d) * 8 + (tok & 7);
                    Vh[off] = (unsigned short)f2bf(acc[i][j][r]);
                }
            }
    } else {
#pragma unroll
        for (int i = 0; i < 4; i++)
#pragma unroll
            for (int r = 0; r < 4; r++) {
                int m = m0 + wr * 64 + i * 16 + quad * 4 + r;
                int bbk = m >> 11, s = m & (Sc - 1);
#pragma unroll
                for (int jp = 0; jp < 2; jp++) {
                    int d = jp * 16 + l;                       // 0..31
                    float cs = ct[s * 32 + d];
                    float sn = st_[s * 32 + d];
                    float x0 = acc[i][jp][r];
                    float x1 = acc[i][jp + 2][r];
                    float y0 = x0 * cs - x1 * sn;
                    float y1 = x1 * cs + x0 * sn;
                    if (z == 0) {
                        size_t rowb = (((size_t)(bbk * Hc + hcol)) * Sc + s) * HDc;
                        Qh[rowb + d]      = (unsigned short)f2bf(y0 * QSC);
                        Qh[rowb + d + 32] = (unsigned short)f2bf(y1 * QSC);
                    } else {
                        int T = s >> 6, tok = s & 63;
                        size_t tb = (((size_t)(bbk * Hc + hcol)) * 32 + T) * 8;
                        size_t off0 = ((tb + (d >> 3)) * 64 + tok) * 8 + (d & 7);
                        size_t off1 = ((tb + (d >> 3) + 4) * 64 + tok) * 8 + (d & 7);
                        Kh[off0] = (unsigned short)f2bf(y0);
                        Kh[off1] = (unsigned short)f2bf(y1);
                    }
                }
            }
    }
}

// ---------------------------------------------------------------------------
// MFMA flash attention v5: single-bf16 Q/K/V, P trunc-bf16, no-rescale
// softmax, double-buffered DMA staging, 128 q-rows/block.
// ---------------------------------------------------------------------------
__global__ __launch_bounds__(256) void attn5(
    const unsigned short* __restrict__ Qh,
    const unsigned short* __restrict__ Kh,
    const unsigned short* __restrict__ Vh,
    unsigned short* __restrict__ AOh, unsigned short* __restrict__ AOl) {
    __shared__ __align__(16) unsigned short KsH[2 * 4096], VtH[2 * 4096];
    __shared__ __align__(16) unsigned short Ph[128 * 72];

    const int t = threadIdx.x;
    const int lane = t & 63;
    const int wave = t >> 6;
    const int l = lane & 15;
    const int quad = lane >> 4;
    // XCD-aware swizzle: cluster 4 bh per XCD for K/V L2 locality.
    const int id = blockIdx.x;                 // 0..511
    const int bh = (id & 7) * 4 + (id >> 7);
    const int qt = (id >> 3) & 15;
    const int q0 = qt * 128;
    const int b = bh >> 4;
    const int hh = bh & 15;

    const bf16x8 ONES = {(short)0x3F80, (short)0x3F80, (short)0x3F80, (short)0x3F80,
                         (short)0x3F80, (short)0x3F80, (short)0x3F80, (short)0x3F80};

    // Q fragments (single bf16, pre-RoPE'd, pre-scaled by QSC)
    bf16x8 qf[2][2];
#pragma unroll
    for (int bnd = 0; bnd < 2; bnd++) {
        size_t rowb = ((size_t)bh * Sc + q0 + bnd * 64 + wave * 16 + l) * HDc;
#pragma unroll
        for (int ks = 0; ks < 2; ks++)
            qf[bnd][ks] = *(const bf16x8*)(Qh + rowb + ks * 32 + quad * 8);
    }

    f32x4 o[2][4], lac[2];
#pragma unroll
    for (int bnd = 0; bnd < 2; bnd++) {
        lac[bnd] = (f32x4){0.f, 0.f, 0.f, 0.f};
#pragma unroll
        for (int i = 0; i < 4; i++) o[bnd][i] = (f32x4){0.f, 0.f, 0.f, 0.f};
    }

    // staging: wave = (tensor<<1)|chunkgroup, q = chunk-in-group.
    const int s_tensor = wave >> 1;
    const int s_cg = wave & 1;
    unsigned short* larr = s_tensor ? VtH : KsH;
    const unsigned short* gB =
        (s_tensor ? Vh : Kh) + (size_t)bh * Sc * HDc + (s_cg * 4) * 512 + lane * 8;

    // preload tile 0
#pragma unroll
    for (int q = 0; q < 4; q++)
        __builtin_amdgcn_global_load_lds(
            (const __attribute__((address_space(1))) unsigned int*)(gB + q * 512),
            (__attribute__((address_space(3))) unsigned int*)(larr + (s_cg * 4 + q) * 512),
            16, 0, 0);

    for (int kt = 0; kt < 32; kt++) {
        __syncthreads();   // drains DMA for buf[kt&1]; fences prev compute
        if (kt + 1 < 32) {
            const unsigned short* g = gB + (size_t)(kt + 1) * 4096;
            unsigned short* buf = larr + ((kt + 1) & 1) * 4096;
#pragma unroll
            for (int q = 0; q < 4; q++)
                __builtin_amdgcn_global_load_lds(
                    (const __attribute__((address_space(1))) unsigned int*)(g + q * 512),
                    (__attribute__((address_space(3))) unsigned int*)(buf + (s_cg * 4 + q) * 512),
                    16, 0, 0);
        }
        const unsigned short* Kbuf = KsH + (kt & 1) * 4096;
        const unsigned short* Vbuf = VtH + (kt & 1) * 4096;

        // ---- S = Q @ K^T, both bands, K frags read once ----
        f32x4 s[2][4];
#pragma unroll
        for (int bnd = 0; bnd < 2; bnd++)
#pragma unroll
            for (int tt = 0; tt < 4; tt++) s[bnd][tt] = (f32x4){0.f, 0.f, 0.f, 0.f};
#pragma unroll
        for (int ks = 0; ks < 2; ks++)
#pragma unroll
            for (int tt = 0; tt < 4; tt++) {
                bf16x8 kf = *(const bf16x8*)&Kbuf[((ks * 4 + quad) * 64 + tt * 16 + l) * 8];
                s[0][tt] = __builtin_amdgcn_mfma_f32_16x16x32_bf16(qf[0][ks], kf, s[0][tt], 0, 0, 0);
                s[1][tt] = __builtin_amdgcn_mfma_f32_16x16x32_bf16(qf[1][ks], kf, s[1][tt], 0, 0, 0);
            }

        // ---- P = exp2(S), trunc-bf16, no rescale ----
#pragma unroll
        for (int bnd = 0; bnd < 2; bnd++)
#pragma unroll
            for (int r = 0; r < 4; r++) {
                const int prow = (bnd * 64 + wave * 16 + quad * 4 + r) * 72;
#pragma unroll
                for (int tt = 0; tt < 4; tt++) {
                    float p = exp2f(s[bnd][tt][r]);
                    Ph[prow + tt * 16 + l] = (unsigned short)(__float_as_uint(p) >> 16);
                }
            }

        // ---- O += P @ V, l += P @ 1; V frags shared across bands ----
#pragma unroll
        for (int ks = 0; ks < 2; ks++) {
            const int p0 = (wave * 16 + l) * 72 + ks * 32 + quad * 8;
            bf16x8 aph0 = *(const bf16x8*)&Ph[p0];
            bf16x8 aph1 = *(const bf16x8*)&Ph[p0 + 64 * 72];
            lac[0] = __builtin_amdgcn_mfma_f32_16x16x32_bf16(aph0, ONES, lac[0], 0, 0, 0);
            lac[1] = __builtin_amdgcn_mfma_f32_16x16x32_bf16(aph1, ONES, lac[1], 0, 0, 0);
#pragma unroll
            for (int tt = 0; tt < 4; tt++) {
                bf16x8 bvh = *(const bf16x8*)&Vbuf[((ks * 4 + quad) * 64 + tt * 16 + l) * 8];
                o[0][tt] = __builtin_amdgcn_mfma_f32_16x16x32_bf16(aph0, bvh, o[0][tt], 0, 0, 0);
                o[1][tt] = __builtin_amdgcn_mfma_f32_16x16x32_bf16(aph1, bvh, o[1][tt], 0, 0, 0);
            }
        }
    }

    // ---- epilogue: normalize + split AO to bf16 hi/lo [B,S,D] ----
#pragma unroll
    for (int bnd = 0; bnd < 2; bnd++)
#pragma unroll
        for (int r = 0; r < 4; r++) {
            float inv = 1.f / lac[bnd][r];
            int q = q0 + bnd * 64 + wave * 16 + quad * 4 + r;
            size_t rowb = ((size_t)b * Sc + q) * Dc + hh * HDc;
#pragma unroll
            for (int tt = 0; tt < 4; tt++) {
                unsigned short h_, l_;
                split2(o[bnd][tt][r] * inv, h_, l_);
                AOh[rowb + tt * 16 + l] = h_;
                AOl[rowb + tt * 16 + l] = l_;
            }
        }
}

// ---------------------------------------------------------------------------
// Output projection GEMM (MFMA split-bf16 3-product, dbuf), fp32 store.
// ---------------------------------------------------------------------------
__global__ __launch_bounds__(256) void gemm_out(
    const unsigned short* __restrict__ Ah, const unsigned short* __restrict__ Al,
    const unsigned short* __restrict__ Wh, const unsigned short* __restrict__ Wl,
    float* __restrict__ C) {
    constexpr int K = 1024;
    __shared__ __align__(16) unsigned short AsH[2 * 4096], AsL[2 * 4096],
                                            BsH[2 * 4096], BsL[2 * 4096];

    const int t = threadIdx.x;
    const int lane = t & 63;
    const int wave = t >> 6;
    const int l = lane & 15;
    const int quad = lane >> 4;
    const int wr = wave >> 1, wc = wave & 1;
    const int m0 = blockIdx.x * 128;   // m fastest -> XCD A-locality
    const int n0 = blockIdx.y * 128;

    // staging: wave 0 = A-hi, 1 = A-lo, 2 = B-hi, 3 = B-lo; 8 jobs each.
    unsigned short* larr = (wave == 0) ? AsH : (wave == 1) ? AsL : (wave == 2) ? BsH : BsL;
    const unsigned short* garr = (wave == 0) ? Ah : (wave == 1) ? Al : (wave == 2) ? Wh : Wl;
    const int t0 = (wave < 2) ? m0 : n0;

    const unsigned short* gsrc[8];
    int ldst[8];
#pragma unroll
    for (int q = 0; q < 8; q++) {
        int rb = q >> 2;
        int kb = q & 3;
        gsrc[q] = garr + (size_t)(t0 + rb * 64 + lane) * K + kb * 8;
        ldst[q] = (kb * 128 + rb * 64) * 8;
    }

    f32x4 acc[4][4];
#pragma unroll
    for (int i = 0; i < 4; i++)
#pragma unroll
        for (int j = 0; j < 4; j++) acc[i][j] = (f32x4){0.f, 0.f, 0.f, 0.f};

    // preload
#pragma unroll
    for (int q = 0; q < 8; q++)
        __builtin_amdgcn_global_load_lds(
            (const __attribute__((address_space(1))) unsigned int*)gsrc[q],
            (__attribute__((address_space(3))) unsigned int*)(larr + ldst[q]), 16, 0, 0);

    for (int it = 0; it < 32; ++it) {
        __syncthreads();
        if (it + 1 < 32) {
            unsigned short* buf = larr + ((it + 1) & 1) * 4096;
            int koff = (it + 1) * 32;
#pragma unroll
            for (int q = 0; q < 8; q++)
                __builtin_amdgcn_global_load_lds(
                    (const __attribute__((address_space(1))) unsigned int*)(gsrc[q] + koff),
                    (__attribute__((address_space(3))) unsigned int*)(buf + ldst[q]), 16, 0, 0);
        }
        const int bo = (it & 1) * 4096;
        bf16x8 ah[4], al[4], bh[4], bl[4];
#pragma unroll
        for (int i = 0; i < 4; i++) {
            int ra = bo + (quad * 128 + wr * 64 + i * 16 + l) * 8;
            ah[i] = *(const bf16x8*)&AsH[ra];
            al[i] = *(const bf16x8*)&AsL[ra];
            int rb2 = bo + (quad * 128 + wc * 64 + i * 16 + l) * 8;
            bh[i] = *(const bf16x8*)&BsH[rb2];
            bl[i] = *(const bf16x8*)&BsL[rb2];
        }
#pragma unroll
        for (int i = 0; i < 4; i++)
#pragma unroll
            for (int j = 0; j < 4; j++) {
                acc[i][j] = __builtin_amdgcn_mfma_f32_16x16x32_bf16(ah[i], bh[j], acc[i][j], 0, 0, 0);
                acc[i][j] = __builtin_amdgcn_mfma_f32_16x16x32_bf16(al[i], bh[j], acc[i][j], 0, 0, 0);
                acc[i][j] = __builtin_amdgcn_mfma_f32_16x16x32_bf16(ah[i], bl[j], acc[i][j], 0, 0, 0);
            }
    }

#pragma unroll
    for (int i = 0; i < 4; i++)
#pragma unroll
        for (int j = 0; j < 4; j++)
#pragma unroll
            for (int r = 0; r < 4; r++) {
                int m = m0 + wr * 64 + i * 16 + quad * 4 + r;
                int n = n0 + wc * 64 + j * 16 + l;
                C[(size_t)m * Dc + n] = acc[i][j][r];
            }
}

// ---------------------------------------------------------------------------
extern "C" void kernel_launch(void* const* d_in, const int* in_sizes, int n_in,
                              void* d_out, int out_size, void* d_ws, size_t ws_size,
                              hipStream_t stream) {
    const float* x  = (const float*)d_in[0];
    const float* Wq = (const float*)d_in[1];
    const float* Wk = (const float*)d_in[2];
    const float* Wv = (const float*)d_in[3];
    const float* Wo = (const float*)d_in[4];
    float* out = (float*)d_out;

    unsigned short* usw = (unsigned short*)d_ws;
    const size_t M4 = (size_t)1 << 22;   // 4M elements
    unsigned short* whAll = usw;                 // 4 x 1M weights hi
    unsigned short* wlAll = usw + M4;            // lo (only Wo slot used)
    unsigned short* xh = usw + 2 * M4;           // x hi (later AOh)
    unsigned short* xl = usw + 3 * M4;           // later AOl
    unsigned short* Qh = usw + 4 * M4;
    unsigned short* Kh = usw + 5 * M4;
    unsigned short* Vh = usw + 6 * M4;
    float* ct = (float*)(usw + 7 * M4);
    float* st_ = ct + (size_t)Sc * 32;
    unsigned short* AOh = xh;   // x dead after QKV GEMM
    unsigned short* AOl = xl;

    // 1. RoPE table
    rope_table<<<dim3((Sc * 32) / 256), dim3(256), 0, stream>>>(ct, st_);
    // 2. convert x + weights to bf16 (Wo keeps hi/lo)
    split_xw<<<dim3(4096, 5), dim3(256), 0, stream>>>(x, Wq, Wk, Wv, Wo, xh, whAll, wlAll);
    // 3. QKV projections (1-product bf16, dbuf) with fused RoPE/scale epilogues
    gemm_qkv<<<dim3(32, 8, 3), dim3(256), 0, stream>>>(
        xh, whAll, Qh, Kh, Vh, ct, st_);
    // 4. attention (single-bf16, no-rescale, dbuf) -> AOh/AOl
    attn5<<<dim3(512), dim3(256), 0, stream>>>(Qh, Kh, Vh, AOh, AOl);
    // 5. output projection (3-product, dbuf)
    gemm_out<<<dim3(32, 8), dim3(256), 0, stream>>>(
        AOh, AOl, whAll + 3 * (1 << 20), wlAll + 3 * (1 << 20), out);
}